// Round 1
// 2043.799 us; speedup vs baseline: 2.6935x; 2.6935x over previous
//
#include <hip/hip_runtime.h>

// ---------- types & helpers ----------
typedef _Float16 half8 __attribute__((ext_vector_type(8)));
typedef float f32x4 __attribute__((ext_vector_type(4)));
typedef _Float16 half2_t __attribute__((ext_vector_type(2)));
typedef const void __attribute__((address_space(1)))* gas_cptr;
typedef void __attribute__((address_space(3)))* las_ptr;

__device__ __forceinline__ unsigned short f2h(float f) {
  return __builtin_bit_cast(unsigned short, (_Float16)f);
}
__device__ __forceinline__ unsigned int packh2(float a, float b) {
  unsigned short lo = __builtin_bit_cast(unsigned short, (_Float16)a);
  unsigned short hi = __builtin_bit_cast(unsigned short, (_Float16)b);
  return (unsigned int)lo | ((unsigned int)hi << 16);
}
__device__ __forceinline__ float fdot2f(unsigned int a, unsigned int b, float c) {
#if __has_builtin(__builtin_amdgcn_fdot2)
  return __builtin_amdgcn_fdot2(__builtin_bit_cast(half2_t, a),
                                __builtin_bit_cast(half2_t, b), c, false);
#else
  half2_t ha = __builtin_bit_cast(half2_t, a), hb = __builtin_bit_cast(half2_t, b);
  return c + (float)ha[0] * (float)hb[0] + (float)ha[1] * (float)hb[1];
#endif
}
__device__ __forceinline__ float fsigm(float x) {
  x = fminf(15.f, fmaxf(-15.f, x));
  return 1.f / (1.f + __expf(-x));
}
__device__ __forceinline__ float ftanhf(float x) {
  x = fminf(15.f, fmaxf(-15.f, x));
  float e = __expf(-2.f * x);
  return (1.f - e) / (1.f + e);
}
__device__ __forceinline__ void stage16(const void* g, void* l) {
  __builtin_amdgcn_global_load_lds((gas_cptr)g, (las_ptr)l, 16, 0, 0);
}

// ---------- small prep kernels ----------
__global__ __launch_bounds__(256) void cvt4(const float4* __restrict__ in,
                                            ushort4* __restrict__ out, int n4) {
  for (int i = blockIdx.x * 256 + threadIdx.x; i < n4; i += gridDim.x * 256) {
    float4 v = in[i];
    ushort4 r;
    r.x = f2h(v.x); r.y = f2h(v.y); r.z = f2h(v.z); r.w = f2h(v.w);
    out[i] = r;
  }
}

// Wih0 (1536 x 300) -> f16 zero-padded to (1536 x 320)
__global__ __launch_bounds__(256) void cvt_pad_wih0(const float* __restrict__ W,
                                                    unsigned short* __restrict__ o) {
  int idx = blockIdx.x * 256 + threadIdx.x;  // < 1536*320
  if (idx >= 1536 * 320) return;
  int r = idx / 320, c = idx - r * 320;
  float v = (c < 300) ? W[(long)r * 300 + c] : 0.f;
  o[idx] = f2h(v);
}

// x = relu(embed[words[:, :-1]]) -> f16, padded E 300->320
__global__ __launch_bounds__(256) void embed_relu(const int* __restrict__ words,
                                                  const float* __restrict__ emb,
                                                  unsigned short* __restrict__ x) {
  int idx = blockIdx.x * 256 + threadIdx.x;  // < 2048*320
  if (idx >= 2048 * 320) return;
  int row = idx / 320, e = idx - row * 320;
  int b = row >> 6, t = row & 63;
  int w = words[b * 65 + t];
  float v = 0.f;
  if (e < 300) v = fmaxf(emb[(long)w * 300 + e], 0.f);
  x[idx] = f2h(v);
}

// h0[l] = encoder_hidden[l] + encoder_hidden[2+l]  (layout (2L,B,H)=(4,32,512))
__global__ __launch_bounds__(256) void h0_sum(const float* __restrict__ hid,
                                              float* __restrict__ h0) {
  int idx = blockIdx.x * 256 + threadIdx.x;  // < 32768
  if (idx >= 2 * 32 * 512) return;
  int l = idx >> 14, rem = idx & 16383;
  h0[idx] = hid[l * 16384 + rem] + hid[(2 + l) * 16384 + rem];
}

// Whh (1536x512 f32) -> per-thread-sliced f16 pairs:
// o[((row)*4 + s)*64 + i] = pack(W[row][s*128+2i], W[row][s*128+2i+1]), row=g*512+dim
__global__ __launch_bounds__(256) void pack_whh8(const float* __restrict__ W,
                                                 unsigned int* __restrict__ o) {
  int f = blockIdx.x * 256 + threadIdx.x;  // < 1536*256 = 393216
  if (f >= 393216) return;
  int i = f & 63;
  int s = (f >> 6) & 3;
  int row = f >> 8;  // 0..1535
  const float* p = W + (long)row * 512 + s * 128 + 2 * i;
  o[f] = packh2(p[0], p[1]);
}

// pack h0 (2,32,512 f32) -> hbuf{0,1}[buf=1] as f16 pairs; zero the sync flags
__global__ __launch_bounds__(256) void h0_pack(const float* __restrict__ h0,
                                               unsigned int* __restrict__ hb0,
                                               unsigned int* __restrict__ hb1,
                                               unsigned int* __restrict__ flags) {
  int idx = blockIdx.x * 256 + threadIdx.x;  // < 16384
  if (idx < 64) flags[idx] = 0;
  if (idx >= 16384) return;
  int l = idx >> 13, rem = idx & 8191;  // rem < 32*256
  unsigned int pv = packh2(h0[l * 16384 + 2 * rem], h0[l * 16384 + 2 * rem + 1]);
  (l ? hb1 : hb0)[8192 + rem] = pv;  // buf index 1
}

// enc (32,256,1024) f32 -> encT (32,1024,256) f16
__global__ void transpose_enc(const float* __restrict__ e, unsigned short* __restrict__ et) {
  __shared__ float t[32][33];
  int d0 = blockIdx.x * 32, s0 = blockIdx.y * 32, b = blockIdx.z;
  const float* eb = e + (long)b * 256 * 1024;
  for (int i = threadIdx.y; i < 32; i += 8)
    t[i][threadIdx.x] = eb[(long)(s0 + i) * 1024 + d0 + threadIdx.x];
  __syncthreads();
  unsigned short* eo = et + (long)b * 1024 * 256;
  for (int i = threadIdx.y; i < 32; i += 8)
    eo[(long)(d0 + i) * 256 + s0 + threadIdx.x] = f2h(t[threadIdx.x][i]);
}

// softmax over rows of 256 (scores f32 -> attn f16)
__global__ __launch_bounds__(256) void softmax_rows(const float* __restrict__ s,
                                                    unsigned short* __restrict__ a) {
  int row = blockIdx.x * 4 + (threadIdx.x >> 6);
  int lane = threadIdx.x & 63;
  const float* sr = s + (long)row * 256;
  float v[4], m = -1e30f;
#pragma unroll
  for (int i = 0; i < 4; i++) { v[i] = sr[lane + 64 * i]; m = fmaxf(m, v[i]); }
#pragma unroll
  for (int o = 32; o; o >>= 1) m = fmaxf(m, __shfl_xor(m, o));
  float sum = 0.f;
#pragma unroll
  for (int i = 0; i < 4; i++) { v[i] = __expf(v[i] - m); sum += v[i]; }
#pragma unroll
  for (int o = 32; o; o >>= 1) sum += __shfl_xor(sum, o);
  float inv = 1.f / sum;
#pragma unroll
  for (int i = 0; i < 4; i++) a[(long)row * 256 + lane + 64 * i] = f2h(v[i] * inv);
}

// ---------- MFMA GEMM: C(MxN) = A(MxK) * B(NxK)^T (+bias) (+relu) ----------
template <int BM, int BN, int WM, int WN, bool OUT_F16, bool HAS_BIAS, bool RELU>
__global__ __launch_bounds__(WM * WN * 64) void gemm_bt(
    const unsigned short* __restrict__ A, const unsigned short* __restrict__ B,
    void* __restrict__ Cv, const float* __restrict__ bias, int K, int lda, int ldb,
    int ldc, long sA, long sB, long sC) {
  constexpr int NT = WM * WN * 64;
  constexpr int IA = (BM * 32) / (NT * 8);
  constexpr int IB = (BN * 32) / (NT * 8);
  static_assert((BM * 32) % (NT * 8) == 0 && (BN * 32) % (NT * 8) == 0, "staging");
  __shared__ __align__(16) unsigned short As[BM * 32];
  __shared__ __align__(16) unsigned short Bs[BN * 32];
  const int tid = threadIdx.x;
  const int wave = tid >> 6, lane = tid & 63;
  const int wm = wave / WN, wn = wave % WN;
  const int lr = lane & 15, lq = lane >> 4;
  const long z = blockIdx.z;
  const unsigned short* Ab = A + z * sA + (long)blockIdx.y * BM * lda;
  const unsigned short* Bb = B + z * sB + (long)blockIdx.x * BN * ldb;

  f32x4 acc[4][4];
#pragma unroll
  for (int i = 0; i < 4; i++)
#pragma unroll
    for (int j = 0; j < 4; j++) acc[i][j] = (f32x4){0.f, 0.f, 0.f, 0.f};

  for (int k0 = 0; k0 < K; k0 += 32) {
#pragma unroll
    for (int i = 0; i < IA; i++) {
      int flat = (i * NT + tid) * 8;
      int r = flat >> 5, c = flat & 31;
      stage16(Ab + (long)r * lda + k0 + c, &As[(i * NT + wave * 64) * 8]);
    }
#pragma unroll
    for (int i = 0; i < IB; i++) {
      int flat = (i * NT + tid) * 8;
      int r = flat >> 5, c = flat & 31;
      stage16(Bb + (long)r * ldb + k0 + c, &Bs[(i * NT + wave * 64) * 8]);
    }
    __syncthreads();
    half8 af[4], bf[4];
#pragma unroll
    for (int t = 0; t < 4; t++)
      af[t] = *(const half8*)&As[(wm * 64 + t * 16 + lr) * 32 + lq * 8];
#pragma unroll
    for (int t = 0; t < 4; t++)
      bf[t] = *(const half8*)&Bs[(wn * 64 + t * 16 + lr) * 32 + lq * 8];
#pragma unroll
    for (int ti = 0; ti < 4; ti++)
#pragma unroll
      for (int tj = 0; tj < 4; tj++)
        acc[ti][tj] = __builtin_amdgcn_mfma_f32_16x16x32_f16(af[ti], bf[tj],
                                                             acc[ti][tj], 0, 0, 0);
    __syncthreads();
  }

  const long crow0 = (long)blockIdx.y * BM + wm * 64;
  const long ccol0 = (long)blockIdx.x * BN + wn * 64;
  float bv[4];
  if constexpr (HAS_BIAS) {
#pragma unroll
    for (int tj = 0; tj < 4; tj++) bv[tj] = bias[ccol0 + tj * 16 + lr];
  }
#pragma unroll
  for (int ti = 0; ti < 4; ti++)
#pragma unroll
    for (int tj = 0; tj < 4; tj++) {
      long col = ccol0 + tj * 16 + lr;
#pragma unroll
      for (int r = 0; r < 4; r++) {
        long row = crow0 + ti * 16 + lq * 4 + r;
        float v = acc[ti][tj][r];
        if constexpr (HAS_BIAS) v += bv[tj];
        if constexpr (RELU) v = fmaxf(v, 0.f);
        if constexpr (OUT_F16)
          ((unsigned short*)Cv)[z * sC + row * ldc + col] = f2h(v);
        else
          ((float*)Cv)[z * sC + row * ldc + col] = v;
      }
    }
}

// ---------- GRU scan v2: 8 blocks per batch, weights truly register-resident ----
// grid = 256 blocks (batch = blockIdx&31, chunk c = blockIdx>>5 owns dims [64c,64c+64)).
// block = 256 threads: ld = tid>>2 (local dim), s = tid&3 (K-slice of 128).
// Per-thread weights: 3 gates x 64 packed u32 = 192 VGPRs (no spill; launch_bounds(256,1)).
// Cross-block h exchange: double-buffered packed-f16 hbuf + per-batch cumulative flag,
// device-scope release/acquire atomics. All 256 blocks co-resident (grid <= #CU) so
// spinning is deadlock-free; flag>=8t implies every block finished step t-1 (induction),
// so skew <= 1 step and two h buffers suffice.
__global__ __launch_bounds__(256, 1) void gru_scan8(
    const float* __restrict__ gi,        // (2048, 1536) f32 (includes bih)
    const unsigned int* __restrict__ wp, // packed per pack_whh8
    const float* __restrict__ bhh,       // (1536,)
    const float* __restrict__ h0,        // (32, 512) f32 for this layer
    unsigned int* __restrict__ hbuf,     // (2, 32, 256) u32 pairs; buf1 prefilled w/ h0
    unsigned int* __restrict__ flag,     // (32,) zeroed
    unsigned short* __restrict__ out, int ldo) {
  const int b = blockIdx.x & 31;
  const int c = blockIdx.x >> 5;
  const int tid = threadIdx.x;
  const int ld = tid >> 2, s = tid & 3;
  const int dim = c * 64 + ld;
  __shared__ __align__(16) unsigned int hp[4 * 68];

  // load weights into registers (rows g*512+dim, K-slice s)
  unsigned int w0[64], w1[64], w2[64];
  {
    const uint4* p0 = (const uint4*)(wp + ((long)(0 * 512 + dim) * 4 + s) * 64);
    const uint4* p1 = (const uint4*)(wp + ((long)(512 + dim) * 4 + s) * 64);
    const uint4* p2 = (const uint4*)(wp + ((long)(1024 + dim) * 4 + s) * 64);
#pragma unroll
    for (int i = 0; i < 16; i++) {
      uint4 v = p0[i];
      w0[4 * i] = v.x; w0[4 * i + 1] = v.y; w0[4 * i + 2] = v.z; w0[4 * i + 3] = v.w;
    }
#pragma unroll
    for (int i = 0; i < 16; i++) {
      uint4 v = p1[i];
      w1[4 * i] = v.x; w1[4 * i + 1] = v.y; w1[4 * i + 2] = v.z; w1[4 * i + 3] = v.w;
    }
#pragma unroll
    for (int i = 0; i < 16; i++) {
      uint4 v = p2[i];
      w2[4 * i] = v.x; w2[4 * i + 1] = v.y; w2[4 * i + 2] = v.z; w2[4 * i + 3] = v.w;
    }
  }
  const bool lead = (s == 0);
  float hprev = 0.f, br = 0.f, bz = 0.f, bn = 0.f;
  if (lead) {
    hprev = h0[b * 512 + dim];
    br = bhh[dim]; bz = bhh[512 + dim]; bn = bhh[1024 + dim];
  }
  unsigned int* myflag = flag + b;

  for (int t = 0; t < 64; t++) {
    const long row = (long)b * 64 + t;
    // gi loads: independent of h, issue before the spin so latency hides
    float gr = 0.f, gz = 0.f, gn = 0.f;
    if (lead) {
      gr = gi[row * 1536 + dim];
      gz = gi[row * 1536 + 512 + dim];
      gn = gi[row * 1536 + 1024 + dim];
    }
    // wave 0: wait for h(t-1), then stage packed pairs into LDS (padded slices)
    if (tid < 64) {
      if (t > 0) {
        unsigned int tgt = 8u * (unsigned int)t;
        unsigned int guard = 0;
        while (__hip_atomic_load(myflag, __ATOMIC_ACQUIRE,
                                 __HIP_MEMORY_SCOPE_AGENT) < tgt) {
          __builtin_amdgcn_s_sleep(1);
          if (++guard > (1u << 20)) break;  // safety valve, never expected
        }
      }
      unsigned int* src = hbuf + ((long)(((t + 1) & 1) * 32 + b)) * 256;
#pragma unroll
      for (int i = 0; i < 4; i++) {
        unsigned int v = __hip_atomic_load(src + i * 64 + tid, __ATOMIC_RELAXED,
                                           __HIP_MEMORY_SCOPE_AGENT);
        hp[i * 68 + tid] = v;
      }
    }
    __syncthreads();
    // 3x128-MAC dot from register weights x LDS h-slice
    float ar = 0.f, az = 0.f, an = 0.f;
    const uint4* hv4 = (const uint4*)(hp + s * 68);
#pragma unroll
    for (int m = 0; m < 16; m++) {
      uint4 hv = hv4[m];
      ar = fdot2f(hv.x, w0[4 * m], ar);
      az = fdot2f(hv.x, w1[4 * m], az);
      an = fdot2f(hv.x, w2[4 * m], an);
      ar = fdot2f(hv.y, w0[4 * m + 1], ar);
      az = fdot2f(hv.y, w1[4 * m + 1], az);
      an = fdot2f(hv.y, w2[4 * m + 1], an);
      ar = fdot2f(hv.z, w0[4 * m + 2], ar);
      az = fdot2f(hv.z, w1[4 * m + 2], az);
      an = fdot2f(hv.z, w2[4 * m + 2], an);
      ar = fdot2f(hv.w, w0[4 * m + 3], ar);
      az = fdot2f(hv.w, w1[4 * m + 3], az);
      an = fdot2f(hv.w, w2[4 * m + 3], an);
    }
    ar += __shfl_xor(ar, 1); ar += __shfl_xor(ar, 2);
    az += __shfl_xor(az, 1); az += __shfl_xor(az, 2);
    an += __shfl_xor(an, 1); an += __shfl_xor(an, 2);
    float hn = 0.f;
    if (lead) {
      float r = fsigm(gr + br + ar);
      float zz = fsigm(gz + bz + az);
      float nn = ftanhf(gn + r * (an + bn));
      hn = (1.f - zz) * nn + zz * hprev;
      hprev = hn;
      out[row * ldo + dim] = f2h(hn);
    }
    // publish new h chunk (even-ld leaders pack pairs with their odd neighbor)
    float ho = __shfl_xor(hn, 4);
    if (lead && ((ld & 1) == 0)) {
      unsigned int pv = packh2(hn, ho);
      unsigned int* dst =
          hbuf + ((long)((t & 1) * 32 + b)) * 256 + c * 32 + (ld >> 1);
      __hip_atomic_store(dst, pv, __ATOMIC_RELAXED, __HIP_MEMORY_SCOPE_AGENT);
    }
    __syncthreads();  // drains vmcnt: all publishes complete before the flag add
    if (tid == 0)
      __hip_atomic_fetch_add(myflag, 1u, __ATOMIC_RELEASE, __HIP_MEMORY_SCOPE_AGENT);
  }
}

// ---------- launch ----------
extern "C" void kernel_launch(void* const* d_in, const int* in_sizes, int n_in,
                              void* d_out, int out_size, void* d_ws, size_t ws_size,
                              hipStream_t stream) {
  const float* enc = (const float*)d_in[0];
  const float* ehid = (const float*)d_in[1];
  const int* words = (const int*)d_in[2];
  const float* embed = (const float*)d_in[3];
  const float* Wih0 = (const float*)d_in[4];
  const float* Whh0 = (const float*)d_in[5];
  const float* bih0 = (const float*)d_in[6];
  const float* bhh0 = (const float*)d_in[7];
  const float* Wih1 = (const float*)d_in[8];
  const float* Whh1 = (const float*)d_in[9];
  const float* bih1 = (const float*)d_in[10];
  const float* bhh1 = (const float*)d_in[11];
  const float* attW = (const float*)d_in[12];
  const float* attb = (const float*)d_in[13];
  const float* awW = (const float*)d_in[14];
  const float* awb = (const float*)d_in[15];
  const float* outW = (const float*)d_in[16];
  const float* outb = (const float*)d_in[17];
  float* out = (float*)d_out;

  char* ws = (char*)d_ws;
  size_t off = 0;
  auto alloc = [&](size_t bytes) {
    char* p = ws + off;
    off = (off + bytes + 255) & ~(size_t)255;
    return p;
  };
  unsigned short* xpad = (unsigned short*)alloc(2048ULL * 320 * 2);
  unsigned short* wih0p = (unsigned short*)alloc(1536ULL * 320 * 2);
  unsigned short* wih1b = (unsigned short*)alloc(1536ULL * 512 * 2);
  unsigned short* attwb = (unsigned short*)alloc(512ULL * 1024 * 2);
  unsigned short* awwb = (unsigned short*)alloc(1536ULL * 1536 * 2);
  unsigned short* outwb = (unsigned short*)alloc(32000ULL * 1536 * 2);
  unsigned short* encb = (unsigned short*)alloc(8192ULL * 1024 * 2);
  unsigned short* enct = (unsigned short*)alloc(32ULL * 1024 * 256 * 2);
  unsigned int* wp0 = (unsigned int*)alloc(393216ULL * 4);
  unsigned int* wp1 = (unsigned int*)alloc(393216ULL * 4);
  float* h0b = (float*)alloc(2ULL * 32 * 512 * 4);
  unsigned int* hbuf0 = (unsigned int*)alloc(2ULL * 32 * 256 * 4);
  unsigned int* hbuf1 = (unsigned int*)alloc(2ULL * 32 * 256 * 4);
  unsigned int* flagsb = (unsigned int*)alloc(64ULL * 4);
  float* gi0 = (float*)alloc(2048ULL * 1536 * 4);
  float* gi1 = (float*)alloc(2048ULL * 1536 * 4);
  unsigned short* ys0 = (unsigned short*)alloc(2048ULL * 512 * 2);
  unsigned short* projb = (unsigned short*)alloc(8192ULL * 512 * 2);
  float* scores = (float*)alloc(2048ULL * 256 * 4);
  unsigned short* attnb = (unsigned short*)alloc(2048ULL * 256 * 2);
  unsigned short* catb = (unsigned short*)alloc(2048ULL * 1536 * 2);
  unsigned short* obuf = (unsigned short*)alloc(2048ULL * 1536 * 2);
  (void)ws_size; (void)in_sizes; (void)n_in; (void)out_size;

  // prep / converts
  cvt4<<<4096, 256, 0, stream>>>((const float4*)enc, (ushort4*)encb, 2097152);
  cvt4<<<1024, 256, 0, stream>>>((const float4*)attW, (ushort4*)attwb, 131072);
  cvt4<<<2048, 256, 0, stream>>>((const float4*)awW, (ushort4*)awwb, 589824);
  cvt4<<<4096, 256, 0, stream>>>((const float4*)outW, (ushort4*)outwb, 12288000);
  cvt4<<<768, 256, 0, stream>>>((const float4*)Wih1, (ushort4*)wih1b, 196608);
  cvt_pad_wih0<<<1920, 256, 0, stream>>>(Wih0, wih0p);
  transpose_enc<<<dim3(32, 8, 32), dim3(32, 8), 0, stream>>>(enc, enct);
  pack_whh8<<<1536, 256, 0, stream>>>(Whh0, wp0);
  pack_whh8<<<1536, 256, 0, stream>>>(Whh1, wp1);
  embed_relu<<<2560, 256, 0, stream>>>(words, embed, xpad);
  h0_sum<<<128, 256, 0, stream>>>(ehid, h0b);
  h0_pack<<<64, 256, 0, stream>>>(h0b, hbuf0, hbuf1, flagsb);

  // gi0 = x @ Wih0^T + bih0   (M=2048,K=320,N=1536) fp32
  gemm_bt<128, 128, 2, 2, false, true, false><<<dim3(12, 16, 1), 256, 0, stream>>>(
      xpad, wih0p, gi0, bih0, 320, 320, 320, 1536, 0, 0, 0);
  // GRU layer 0 -> ys0 f16
  gru_scan8<<<256, 256, 0, stream>>>(gi0, wp0, bhh0, h0b, hbuf0, flagsb, ys0, 512);
  // gi1 = ys0 @ Wih1^T + bih1
  gemm_bt<128, 128, 2, 2, false, true, false><<<dim3(12, 16, 1), 256, 0, stream>>>(
      ys0, wih1b, gi1, bih1, 512, 512, 512, 1536, 0, 0, 0);
  // GRU layer 1 -> cat[:, 0:512] f16
  gru_scan8<<<256, 256, 0, stream>>>(gi1, wp1, bhh1, h0b + 16384, hbuf1,
                                     flagsb + 32, catb, 1536);
  // proj = enc @ attn_W^T + attn_b  (M=8192,K=1024,N=512) f16
  gemm_bt<128, 128, 2, 2, true, true, false><<<dim3(4, 64, 1), 256, 0, stream>>>(
      encb, attwb, projb, attb, 1024, 1024, 1024, 512, 0, 0, 0);
  // scores[b] = h[b] @ proj[b]^T  (batched M=64,N=256,K=512) fp32
  gemm_bt<64, 128, 1, 2, false, false, false><<<dim3(2, 1, 32), 128, 0, stream>>>(
      catb, projb, scores, nullptr, 512, 1536, 512, 256,
      64L * 1536, 256L * 512, 64L * 256);
  softmax_rows<<<512, 256, 0, stream>>>(scores, attnb);
  // ctx[b] = attn[b] @ encT[b]^T  (batched M=64,N=1024,K=256) -> cat[:, 512:]
  gemm_bt<64, 128, 1, 2, true, false, false><<<dim3(8, 1, 32), 128, 0, stream>>>(
      attnb, enct, catb + 512, nullptr, 256, 256, 256, 1536,
      64L * 256, 1024L * 256, 64L * 1536);
  // o = relu(cat @ aw_W^T + aw_b)  (M=2048,K=1536,N=1536) f16
  gemm_bt<128, 128, 2, 2, true, true, true><<<dim3(12, 16, 1), 256, 0, stream>>>(
      catb, awwb, obuf, awb, 1536, 1536, 1536, 1536, 0, 0, 0);
  // logits = o @ out_W^T + out_b  (M=2048,K=1536,N=32000) fp32 -> d_out
  gemm_bt<128, 128, 2, 2, false, true, false><<<dim3(250, 16, 1), 256, 0, stream>>>(
      obuf, outwb, out, outb, 1536, 1536, 1536, 32000, 0, 0, 0);
}

// Round 2
// 1133.851 us; speedup vs baseline: 4.8551x; 1.8025x over previous
//
#include <hip/hip_runtime.h>

// ---------- types & helpers ----------
typedef _Float16 half8 __attribute__((ext_vector_type(8)));
typedef float f32x4 __attribute__((ext_vector_type(4)));
typedef _Float16 half2_t __attribute__((ext_vector_type(2)));
typedef const void __attribute__((address_space(1)))* gas_cptr;
typedef void __attribute__((address_space(3)))* las_ptr;

__device__ __forceinline__ unsigned short f2h(float f) {
  return __builtin_bit_cast(unsigned short, (_Float16)f);
}
__device__ __forceinline__ unsigned int packh2(float a, float b) {
  unsigned short lo = __builtin_bit_cast(unsigned short, (_Float16)a);
  unsigned short hi = __builtin_bit_cast(unsigned short, (_Float16)b);
  return (unsigned int)lo | ((unsigned int)hi << 16);
}
__device__ __forceinline__ float fdot2f(unsigned int a, unsigned int b, float c) {
#if __has_builtin(__builtin_amdgcn_fdot2)
  return __builtin_amdgcn_fdot2(__builtin_bit_cast(half2_t, a),
                                __builtin_bit_cast(half2_t, b), c, false);
#else
  half2_t ha = __builtin_bit_cast(half2_t, a), hb = __builtin_bit_cast(half2_t, b);
  return c + (float)ha[0] * (float)hb[0] + (float)ha[1] * (float)hb[1];
#endif
}
__device__ __forceinline__ float fsigm(float x) {
  x = fminf(15.f, fmaxf(-15.f, x));
  return 1.f / (1.f + __expf(-x));
}
__device__ __forceinline__ float ftanhf(float x) {
  x = fminf(15.f, fmaxf(-15.f, x));
  float e = __expf(-2.f * x);
  return (1.f - e) / (1.f + e);
}
__device__ __forceinline__ void stage16(const void* g, void* l) {
  __builtin_amdgcn_global_load_lds((gas_cptr)g, (las_ptr)l, 16, 0, 0);
}

// ---------- small prep kernels ----------
__global__ __launch_bounds__(256) void cvt4(const float4* __restrict__ in,
                                            ushort4* __restrict__ out, int n4) {
  for (int i = blockIdx.x * 256 + threadIdx.x; i < n4; i += gridDim.x * 256) {
    float4 v = in[i];
    ushort4 r;
    r.x = f2h(v.x); r.y = f2h(v.y); r.z = f2h(v.z); r.w = f2h(v.w);
    out[i] = r;
  }
}

// Wih0 (1536 x 300) -> f16 zero-padded to (1536 x 320)
__global__ __launch_bounds__(256) void cvt_pad_wih0(const float* __restrict__ W,
                                                    unsigned short* __restrict__ o) {
  int idx = blockIdx.x * 256 + threadIdx.x;  // < 1536*320
  if (idx >= 1536 * 320) return;
  int r = idx / 320, c = idx - r * 320;
  float v = (c < 300) ? W[(long)r * 300 + c] : 0.f;
  o[idx] = f2h(v);
}

// x = relu(embed[words[:, :-1]]) -> f16, padded E 300->320
__global__ __launch_bounds__(256) void embed_relu(const int* __restrict__ words,
                                                  const float* __restrict__ emb,
                                                  unsigned short* __restrict__ x) {
  int idx = blockIdx.x * 256 + threadIdx.x;  // < 2048*320
  if (idx >= 2048 * 320) return;
  int row = idx / 320, e = idx - row * 320;
  int b = row >> 6, t = row & 63;
  int w = words[b * 65 + t];
  float v = 0.f;
  if (e < 300) v = fmaxf(emb[(long)w * 300 + e], 0.f);
  x[idx] = f2h(v);
}

// h0[l] = encoder_hidden[l] + encoder_hidden[2+l]  (layout (2L,B,H)=(4,32,512))
__global__ __launch_bounds__(256) void h0_sum(const float* __restrict__ hid,
                                              float* __restrict__ h0) {
  int idx = blockIdx.x * 256 + threadIdx.x;  // < 32768
  if (idx >= 2 * 32 * 512) return;
  int l = idx >> 14, rem = idx & 16383;
  h0[idx] = hid[l * 16384 + rem] + hid[(2 + l) * 16384 + rem];
}

// Whh (1536x512 f32) -> per-thread-sliced f16 pairs:
// o[((row)*4 + s)*64 + i] = pack(W[row][s*128+2i], W[row][s*128+2i+1]), row=g*512+dim
__global__ __launch_bounds__(256) void pack_whh8(const float* __restrict__ W,
                                                 unsigned int* __restrict__ o) {
  int f = blockIdx.x * 256 + threadIdx.x;  // < 1536*256 = 393216
  if (f >= 393216) return;
  int i = f & 63;
  int s = (f >> 6) & 3;
  int row = f >> 8;  // 0..1535
  const float* p = W + (long)row * 512 + s * 128 + 2 * i;
  o[f] = packh2(p[0], p[1]);
}

// slots[l] is (65, 32, 256) u64. slot[0] prefilled with packed h0 (self-validating
// {pv, ~pv}); slots[1..64] zeroed ({0,0} fails hi==~lo -> "not ready").
__global__ __launch_bounds__(256) void slots_init(const float* __restrict__ h0,
                                                  unsigned long long* __restrict__ s0,
                                                  unsigned long long* __restrict__ s1) {
  const long N = 65L * 32 * 256;  // 532480 per layer
  for (long i = (long)blockIdx.x * 256 + threadIdx.x; i < 2 * N;
       i += (long)gridDim.x * 256) {
    int l = (int)(i / N);
    long r = i - (long)l * N;
    unsigned long long* dst = l ? s1 : s0;
    if (r < 32 * 256) {
      int b = (int)(r >> 8), p = (int)(r & 255);
      unsigned int pv = packh2(h0[l * 16384 + b * 512 + 2 * p],
                               h0[l * 16384 + b * 512 + 2 * p + 1]);
      dst[r] = (unsigned long long)pv | ((unsigned long long)(~pv) << 32);
    } else {
      dst[r] = 0ULL;
    }
  }
}

// enc (32,256,1024) f32 -> encT (32,1024,256) f16
__global__ void transpose_enc(const float* __restrict__ e, unsigned short* __restrict__ et) {
  __shared__ float t[32][33];
  int d0 = blockIdx.x * 32, s0 = blockIdx.y * 32, b = blockIdx.z;
  const float* eb = e + (long)b * 256 * 1024;
  for (int i = threadIdx.y; i < 32; i += 8)
    t[i][threadIdx.x] = eb[(long)(s0 + i) * 1024 + d0 + threadIdx.x];
  __syncthreads();
  unsigned short* eo = et + (long)b * 1024 * 256;
  for (int i = threadIdx.y; i < 32; i += 8)
    eo[(long)(d0 + i) * 256 + s0 + threadIdx.x] = f2h(t[threadIdx.x][i]);
}

// softmax over rows of 256 (scores f32 -> attn f16)
__global__ __launch_bounds__(256) void softmax_rows(const float* __restrict__ s,
                                                    unsigned short* __restrict__ a) {
  int row = blockIdx.x * 4 + (threadIdx.x >> 6);
  int lane = threadIdx.x & 63;
  const float* sr = s + (long)row * 256;
  float v[4], m = -1e30f;
#pragma unroll
  for (int i = 0; i < 4; i++) { v[i] = sr[lane + 64 * i]; m = fmaxf(m, v[i]); }
#pragma unroll
  for (int o = 32; o; o >>= 1) m = fmaxf(m, __shfl_xor(m, o));
  float sum = 0.f;
#pragma unroll
  for (int i = 0; i < 4; i++) { v[i] = __expf(v[i] - m); sum += v[i]; }
#pragma unroll
  for (int o = 32; o; o >>= 1) sum += __shfl_xor(sum, o);
  float inv = 1.f / sum;
#pragma unroll
  for (int i = 0; i < 4; i++) a[(long)row * 256 + lane + 64 * i] = f2h(v[i] * inv);
}

// ---------- MFMA GEMM: C(MxN) = A(MxK) * B(NxK)^T (+bias) (+relu) ----------
template <int BM, int BN, int WM, int WN, bool OUT_F16, bool HAS_BIAS, bool RELU>
__global__ __launch_bounds__(WM * WN * 64) void gemm_bt(
    const unsigned short* __restrict__ A, const unsigned short* __restrict__ B,
    void* __restrict__ Cv, const float* __restrict__ bias, int K, int lda, int ldb,
    int ldc, long sA, long sB, long sC) {
  constexpr int NT = WM * WN * 64;
  constexpr int IA = (BM * 32) / (NT * 8);
  constexpr int IB = (BN * 32) / (NT * 8);
  static_assert((BM * 32) % (NT * 8) == 0 && (BN * 32) % (NT * 8) == 0, "staging");
  __shared__ __align__(16) unsigned short As[BM * 32];
  __shared__ __align__(16) unsigned short Bs[BN * 32];
  const int tid = threadIdx.x;
  const int wave = tid >> 6, lane = tid & 63;
  const int wm = wave / WN, wn = wave % WN;
  const int lr = lane & 15, lq = lane >> 4;
  const long z = blockIdx.z;
  const unsigned short* Ab = A + z * sA + (long)blockIdx.y * BM * lda;
  const unsigned short* Bb = B + z * sB + (long)blockIdx.x * BN * ldb;

  f32x4 acc[4][4];
#pragma unroll
  for (int i = 0; i < 4; i++)
#pragma unroll
    for (int j = 0; j < 4; j++) acc[i][j] = (f32x4){0.f, 0.f, 0.f, 0.f};

  for (int k0 = 0; k0 < K; k0 += 32) {
#pragma unroll
    for (int i = 0; i < IA; i++) {
      int flat = (i * NT + tid) * 8;
      int r = flat >> 5, c = flat & 31;
      stage16(Ab + (long)r * lda + k0 + c, &As[(i * NT + wave * 64) * 8]);
    }
#pragma unroll
    for (int i = 0; i < IB; i++) {
      int flat = (i * NT + tid) * 8;
      int r = flat >> 5, c = flat & 31;
      stage16(Bb + (long)r * ldb + k0 + c, &Bs[(i * NT + wave * 64) * 8]);
    }
    __syncthreads();
    half8 af[4], bf[4];
#pragma unroll
    for (int t = 0; t < 4; t++)
      af[t] = *(const half8*)&As[(wm * 64 + t * 16 + lr) * 32 + lq * 8];
#pragma unroll
    for (int t = 0; t < 4; t++)
      bf[t] = *(const half8*)&Bs[(wn * 64 + t * 16 + lr) * 32 + lq * 8];
#pragma unroll
    for (int ti = 0; ti < 4; ti++)
#pragma unroll
      for (int tj = 0; tj < 4; tj++)
        acc[ti][tj] = __builtin_amdgcn_mfma_f32_16x16x32_f16(af[ti], bf[tj],
                                                             acc[ti][tj], 0, 0, 0);
    __syncthreads();
  }

  const long crow0 = (long)blockIdx.y * BM + wm * 64;
  const long ccol0 = (long)blockIdx.x * BN + wn * 64;
  float bv[4];
  if constexpr (HAS_BIAS) {
#pragma unroll
    for (int tj = 0; tj < 4; tj++) bv[tj] = bias[ccol0 + tj * 16 + lr];
  }
#pragma unroll
  for (int ti = 0; ti < 4; ti++)
#pragma unroll
    for (int tj = 0; tj < 4; tj++) {
      long col = ccol0 + tj * 16 + lr;
#pragma unroll
      for (int r = 0; r < 4; r++) {
        long row = crow0 + ti * 16 + lq * 4 + r;
        float v = acc[ti][tj][r];
        if constexpr (HAS_BIAS) v += bv[tj];
        if constexpr (RELU) v = fmaxf(v, 0.f);
        if constexpr (OUT_F16)
          ((unsigned short*)Cv)[z * sC + row * ldc + col] = f2h(v);
        else
          ((float*)Cv)[z * sC + row * ldc + col] = v;
      }
    }
}

// ---------- GRU scan v3: flagless self-validating slot exchange ----------
// grid = 256 blocks (batch = blockIdx&31, chunk c = blockIdx>>5 owns dims [64c,64c+64)).
// block = 256 threads: ld = tid>>2 (local dim), s = tid&3 (K-slice of 128).
// Weights register-resident (192 u32/thread). Cross-block h exchange:
// write-once slots[t][b][pair] u64 = {pv, ~pv}; validity fused with data, so one
// store->visibility + one poll round trip per step (no flag, no fences, no vmcnt
// drain on the critical path). All 256 blocks co-resident (grid == #CU).
__global__ __launch_bounds__(256, 1) void gru_scan8(
    const float* __restrict__ gi,        // (2048, 1536) f32 (includes bih)
    const unsigned int* __restrict__ wp, // packed per pack_whh8
    const float* __restrict__ bhh,       // (1536,)
    const float* __restrict__ h0,        // (32, 512) f32 for this layer
    unsigned long long* __restrict__ slots,  // (65,32,256) u64, slot[0] prefilled
    unsigned short* __restrict__ out, int ldo) {
  const int b = blockIdx.x & 31;
  const int c = blockIdx.x >> 5;
  const int tid = threadIdx.x;
  const int ld = tid >> 2, s = tid & 3;
  const int dim = c * 64 + ld;
  __shared__ __align__(16) unsigned int hp[2][4 * 68];  // double-buffered h staging

  // load weights into registers (rows g*512+dim, K-slice s)
  unsigned int w0[64], w1[64], w2[64];
  {
    const uint4* p0 = (const uint4*)(wp + ((long)(0 * 512 + dim) * 4 + s) * 64);
    const uint4* p1 = (const uint4*)(wp + ((long)(512 + dim) * 4 + s) * 64);
    const uint4* p2 = (const uint4*)(wp + ((long)(1024 + dim) * 4 + s) * 64);
#pragma unroll
    for (int i = 0; i < 16; i++) {
      uint4 v = p0[i];
      w0[4 * i] = v.x; w0[4 * i + 1] = v.y; w0[4 * i + 2] = v.z; w0[4 * i + 3] = v.w;
    }
#pragma unroll
    for (int i = 0; i < 16; i++) {
      uint4 v = p1[i];
      w1[4 * i] = v.x; w1[4 * i + 1] = v.y; w1[4 * i + 2] = v.z; w1[4 * i + 3] = v.w;
    }
#pragma unroll
    for (int i = 0; i < 16; i++) {
      uint4 v = p2[i];
      w2[4 * i] = v.x; w2[4 * i + 1] = v.y; w2[4 * i + 2] = v.z; w2[4 * i + 3] = v.w;
    }
  }
  const bool lead = (s == 0);
  float hprev = 0.f, br = 0.f, bz = 0.f, bn = 0.f;
  if (lead) {
    hprev = h0[b * 512 + dim];
    br = bhh[dim]; bz = bhh[512 + dim]; bn = bhh[1024 + dim];
  }

  for (int t = 0; t < 64; t++) {
    const long row = (long)b * 64 + t;
    // gi loads: independent of h, issue before the poll so latency hides
    float gr = 0.f, gz = 0.f, gn = 0.f;
    if (lead) {
      gr = gi[row * 1536 + dim];
      gz = gi[row * 1536 + 512 + dim];
      gn = gi[row * 1536 + 1024 + dim];
    }
    // every thread polls exactly one self-validating u64 slot of h(t-1)
    {
      const unsigned long long* sp = slots + ((long)t * 32 + b) * 256 + tid;
      unsigned long long v =
          __hip_atomic_load(sp, __ATOMIC_RELAXED, __HIP_MEMORY_SCOPE_AGENT);
      unsigned int guard = 0;
      while ((unsigned int)(v >> 32) != ~(unsigned int)v) {
        __builtin_amdgcn_s_sleep(1);
        v = __hip_atomic_load(sp, __ATOMIC_RELAXED, __HIP_MEMORY_SCOPE_AGENT);
        if (++guard > (1u << 20)) break;  // safety valve, never expected
      }
      hp[t & 1][(tid >> 6) * 68 + (tid & 63)] = (unsigned int)v;
    }
    __syncthreads();
    // 3x128-MAC dot from register weights x LDS h-slice
    float ar = 0.f, az = 0.f, an = 0.f;
    const uint4* hv4 = (const uint4*)(hp[t & 1] + s * 68);
#pragma unroll
    for (int m = 0; m < 16; m++) {
      uint4 hv = hv4[m];
      ar = fdot2f(hv.x, w0[4 * m], ar);
      az = fdot2f(hv.x, w1[4 * m], az);
      an = fdot2f(hv.x, w2[4 * m], an);
      ar = fdot2f(hv.y, w0[4 * m + 1], ar);
      az = fdot2f(hv.y, w1[4 * m + 1], az);
      an = fdot2f(hv.y, w2[4 * m + 1], an);
      ar = fdot2f(hv.z, w0[4 * m + 2], ar);
      az = fdot2f(hv.z, w1[4 * m + 2], az);
      an = fdot2f(hv.z, w2[4 * m + 2], an);
      ar = fdot2f(hv.w, w0[4 * m + 3], ar);
      az = fdot2f(hv.w, w1[4 * m + 3], az);
      an = fdot2f(hv.w, w2[4 * m + 3], an);
    }
    ar += __shfl_xor(ar, 1); ar += __shfl_xor(ar, 2);
    az += __shfl_xor(az, 1); az += __shfl_xor(az, 2);
    an += __shfl_xor(an, 1); an += __shfl_xor(an, 2);
    float hn = 0.f;
    if (lead) {
      float r = fsigm(gr + br + ar);
      float zz = fsigm(gz + bz + az);
      float nn = ftanhf(gn + r * (an + bn));
      hn = (1.f - zz) * nn + zz * hprev;
      hprev = hn;
      out[row * ldo + dim] = f2h(hn);
    }
    // publish new h chunk: even-ld leaders pack pairs with their odd neighbor;
    // single atomic u64 store carries data + validity together.
    float ho = __shfl_xor(hn, 4);
    if (lead && ((ld & 1) == 0)) {
      unsigned int pv = packh2(hn, ho);
      unsigned long long pw =
          (unsigned long long)pv | ((unsigned long long)(~pv) << 32);
      __hip_atomic_store(slots + ((long)(t + 1) * 32 + b) * 256 + c * 32 + (ld >> 1),
                         pw, __ATOMIC_RELAXED, __HIP_MEMORY_SCOPE_AGENT);
    }
    // no trailing barrier: hp is double-buffered; the next iteration's single
    // barrier orders reads-at-t vs writes-at-t+2 (lgkmcnt(0) drains before barrier).
  }
}

// ---------- launch ----------
extern "C" void kernel_launch(void* const* d_in, const int* in_sizes, int n_in,
                              void* d_out, int out_size, void* d_ws, size_t ws_size,
                              hipStream_t stream) {
  const float* enc = (const float*)d_in[0];
  const float* ehid = (const float*)d_in[1];
  const int* words = (const int*)d_in[2];
  const float* embed = (const float*)d_in[3];
  const float* Wih0 = (const float*)d_in[4];
  const float* Whh0 = (const float*)d_in[5];
  const float* bih0 = (const float*)d_in[6];
  const float* bhh0 = (const float*)d_in[7];
  const float* Wih1 = (const float*)d_in[8];
  const float* Whh1 = (const float*)d_in[9];
  const float* bih1 = (const float*)d_in[10];
  const float* bhh1 = (const float*)d_in[11];
  const float* attW = (const float*)d_in[12];
  const float* attb = (const float*)d_in[13];
  const float* awW = (const float*)d_in[14];
  const float* awb = (const float*)d_in[15];
  const float* outW = (const float*)d_in[16];
  const float* outb = (const float*)d_in[17];
  float* out = (float*)d_out;

  char* ws = (char*)d_ws;
  size_t off = 0;
  auto alloc = [&](size_t bytes) {
    char* p = ws + off;
    off = (off + bytes + 255) & ~(size_t)255;
    return p;
  };
  unsigned short* xpad = (unsigned short*)alloc(2048ULL * 320 * 2);
  unsigned short* wih0p = (unsigned short*)alloc(1536ULL * 320 * 2);
  unsigned short* wih1b = (unsigned short*)alloc(1536ULL * 512 * 2);
  unsigned short* attwb = (unsigned short*)alloc(512ULL * 1024 * 2);
  unsigned short* awwb = (unsigned short*)alloc(1536ULL * 1536 * 2);
  unsigned short* outwb = (unsigned short*)alloc(32000ULL * 1536 * 2);
  unsigned short* encb = (unsigned short*)alloc(8192ULL * 1024 * 2);
  unsigned short* enct = (unsigned short*)alloc(32ULL * 1024 * 256 * 2);
  unsigned int* wp0 = (unsigned int*)alloc(393216ULL * 4);
  unsigned int* wp1 = (unsigned int*)alloc(393216ULL * 4);
  float* h0b = (float*)alloc(2ULL * 32 * 512 * 4);
  unsigned long long* slots0 = (unsigned long long*)alloc(65ULL * 32 * 256 * 8);
  unsigned long long* slots1 = (unsigned long long*)alloc(65ULL * 32 * 256 * 8);
  float* gi0 = (float*)alloc(2048ULL * 1536 * 4);
  float* gi1 = (float*)alloc(2048ULL * 1536 * 4);
  unsigned short* ys0 = (unsigned short*)alloc(2048ULL * 512 * 2);
  unsigned short* projb = (unsigned short*)alloc(8192ULL * 512 * 2);
  float* scores = (float*)alloc(2048ULL * 256 * 4);
  unsigned short* attnb = (unsigned short*)alloc(2048ULL * 256 * 2);
  unsigned short* catb = (unsigned short*)alloc(2048ULL * 1536 * 2);
  unsigned short* obuf = (unsigned short*)alloc(2048ULL * 1536 * 2);
  (void)ws_size; (void)in_sizes; (void)n_in; (void)out_size;

  // prep / converts
  cvt4<<<4096, 256, 0, stream>>>((const float4*)enc, (ushort4*)encb, 2097152);
  cvt4<<<1024, 256, 0, stream>>>((const float4*)attW, (ushort4*)attwb, 131072);
  cvt4<<<2048, 256, 0, stream>>>((const float4*)awW, (ushort4*)awwb, 589824);
  cvt4<<<4096, 256, 0, stream>>>((const float4*)outW, (ushort4*)outwb, 12288000);
  cvt4<<<768, 256, 0, stream>>>((const float4*)Wih1, (ushort4*)wih1b, 196608);
  cvt_pad_wih0<<<1920, 256, 0, stream>>>(Wih0, wih0p);
  transpose_enc<<<dim3(32, 8, 32), dim3(32, 8), 0, stream>>>(enc, enct);
  pack_whh8<<<1536, 256, 0, stream>>>(Whh0, wp0);
  pack_whh8<<<1536, 256, 0, stream>>>(Whh1, wp1);
  embed_relu<<<2560, 256, 0, stream>>>(words, embed, xpad);
  h0_sum<<<128, 256, 0, stream>>>(ehid, h0b);
  slots_init<<<4160, 256, 0, stream>>>(h0b, slots0, slots1);

  // gi0 = x @ Wih0^T + bih0   (M=2048,K=320,N=1536) fp32
  gemm_bt<128, 128, 2, 2, false, true, false><<<dim3(12, 16, 1), 256, 0, stream>>>(
      xpad, wih0p, gi0, bih0, 320, 320, 320, 1536, 0, 0, 0);
  // GRU layer 0 -> ys0 f16
  gru_scan8<<<256, 256, 0, stream>>>(gi0, wp0, bhh0, h0b, slots0, ys0, 512);
  // gi1 = ys0 @ Wih1^T + bih1
  gemm_bt<128, 128, 2, 2, false, true, false><<<dim3(12, 16, 1), 256, 0, stream>>>(
      ys0, wih1b, gi1, bih1, 512, 512, 512, 1536, 0, 0, 0);
  // GRU layer 1 -> cat[:, 0:512] f16
  gru_scan8<<<256, 256, 0, stream>>>(gi1, wp1, bhh1, h0b + 16384, slots1,
                                     catb, 1536);
  // proj = enc @ attn_W^T + attn_b  (M=8192,K=1024,N=512) f16
  gemm_bt<128, 128, 2, 2, true, true, false><<<dim3(4, 64, 1), 256, 0, stream>>>(
      encb, attwb, projb, attb, 1024, 1024, 1024, 512, 0, 0, 0);
  // scores[b] = h[b] @ proj[b]^T  (batched M=64,N=256,K=512) fp32
  gemm_bt<64, 128, 1, 2, false, false, false><<<dim3(2, 1, 32), 128, 0, stream>>>(
      catb, projb, scores, nullptr, 512, 1536, 512, 256,
      64L * 1536, 256L * 512, 64L * 256);
  softmax_rows<<<512, 256, 0, stream>>>(scores, attnb);
  // ctx[b] = attn[b] @ encT[b]^T  (batched M=64,N=1024,K=256) -> cat[:, 512:]
  gemm_bt<64, 128, 1, 2, true, false, false><<<dim3(8, 1, 32), 128, 0, stream>>>(
      attnb, enct, catb + 512, nullptr, 256, 256, 256, 1536,
      64L * 256, 1024L * 256, 64L * 1536);
  // o = relu(cat @ aw_W^T + aw_b)  (M=2048,K=1536,N=1536) f16
  gemm_bt<128, 128, 2, 2, true, true, true><<<dim3(12, 16, 1), 256, 0, stream>>>(
      catb, awwb, obuf, awb, 1536, 1536, 1536, 1536, 0, 0, 0);
  // logits = o @ out_W^T + out_b  (M=2048,K=1536,N=32000) fp32 -> d_out
  gemm_bt<128, 128, 2, 2, false, true, false><<<dim3(250, 16, 1), 256, 0, stream>>>(
      obuf, outwb, out, outb, 1536, 1536, 1536, 32000, 0, 0, 0);
}

// Round 3
// 1115.237 us; speedup vs baseline: 4.9361x; 1.0167x over previous
//
#include <hip/hip_runtime.h>

// ---------- types & helpers ----------
typedef _Float16 half8 __attribute__((ext_vector_type(8)));
typedef float f32x4 __attribute__((ext_vector_type(4)));
typedef _Float16 half2_t __attribute__((ext_vector_type(2)));
typedef const void __attribute__((address_space(1)))* gas_cptr;
typedef void __attribute__((address_space(3)))* las_ptr;

__device__ __forceinline__ unsigned short f2h(float f) {
  return __builtin_bit_cast(unsigned short, (_Float16)f);
}
__device__ __forceinline__ unsigned int packh2(float a, float b) {
  unsigned short lo = __builtin_bit_cast(unsigned short, (_Float16)a);
  unsigned short hi = __builtin_bit_cast(unsigned short, (_Float16)b);
  return (unsigned int)lo | ((unsigned int)hi << 16);
}
__device__ __forceinline__ float fdot2f(unsigned int a, unsigned int b, float c) {
#if __has_builtin(__builtin_amdgcn_fdot2)
  return __builtin_amdgcn_fdot2(__builtin_bit_cast(half2_t, a),
                                __builtin_bit_cast(half2_t, b), c, false);
#else
  half2_t ha = __builtin_bit_cast(half2_t, a), hb = __builtin_bit_cast(half2_t, b);
  return c + (float)ha[0] * (float)hb[0] + (float)ha[1] * (float)hb[1];
#endif
}
__device__ __forceinline__ float fsigm(float x) {
  x = fminf(15.f, fmaxf(-15.f, x));
  return 1.f / (1.f + __expf(-x));
}
__device__ __forceinline__ float ftanhf(float x) {
  x = fminf(15.f, fmaxf(-15.f, x));
  float e = __expf(-2.f * x);
  return (1.f - e) / (1.f + e);
}
__device__ __forceinline__ void stage16(const void* g, void* l) {
  __builtin_amdgcn_global_load_lds((gas_cptr)g, (las_ptr)l, 16, 0, 0);
}

// ---------- small prep kernels ----------
__global__ __launch_bounds__(256) void cvt4(const float4* __restrict__ in,
                                            ushort4* __restrict__ out, int n4) {
  for (int i = blockIdx.x * 256 + threadIdx.x; i < n4; i += gridDim.x * 256) {
    float4 v = in[i];
    ushort4 r;
    r.x = f2h(v.x); r.y = f2h(v.y); r.z = f2h(v.z); r.w = f2h(v.w);
    out[i] = r;
  }
}

// Wih0 (1536 x 300) -> f16 zero-padded to (1536 x 320)
__global__ __launch_bounds__(256) void cvt_pad_wih0(const float* __restrict__ W,
                                                    unsigned short* __restrict__ o) {
  int idx = blockIdx.x * 256 + threadIdx.x;  // < 1536*320
  if (idx >= 1536 * 320) return;
  int r = idx / 320, c = idx - r * 320;
  float v = (c < 300) ? W[(long)r * 300 + c] : 0.f;
  o[idx] = f2h(v);
}

// x = relu(embed[words[:, :-1]]) -> f16, padded E 300->320
__global__ __launch_bounds__(256) void embed_relu(const int* __restrict__ words,
                                                  const float* __restrict__ emb,
                                                  unsigned short* __restrict__ x) {
  int idx = blockIdx.x * 256 + threadIdx.x;  // < 2048*320
  if (idx >= 2048 * 320) return;
  int row = idx / 320, e = idx - row * 320;
  int b = row >> 6, t = row & 63;
  int w = words[b * 65 + t];
  float v = 0.f;
  if (e < 300) v = fmaxf(emb[(long)w * 300 + e], 0.f);
  x[idx] = f2h(v);
}

// h0[l] = encoder_hidden[l] + encoder_hidden[2+l]  (layout (2L,B,H)=(4,32,512))
__global__ __launch_bounds__(256) void h0_sum(const float* __restrict__ hid,
                                              float* __restrict__ h0) {
  int idx = blockIdx.x * 256 + threadIdx.x;  // < 32768
  if (idx >= 2 * 32 * 512) return;
  int l = idx >> 14, rem = idx & 16383;
  h0[idx] = hid[l * 16384 + rem] + hid[(2 + l) * 16384 + rem];
}

// Whh (1536x512 f32) -> per-thread-sliced f16 pairs:
// o[((row)*4 + s)*64 + i] = pack(W[row][s*128+2i], W[row][s*128+2i+1]), row=g*512+dim
__global__ __launch_bounds__(256) void pack_whh8(const float* __restrict__ W,
                                                 unsigned int* __restrict__ o) {
  int f = blockIdx.x * 256 + threadIdx.x;  // < 1536*256 = 393216
  if (f >= 393216) return;
  int i = f & 63;
  int s = (f >> 6) & 3;
  int row = f >> 8;  // 0..1535
  const float* p = W + (long)row * 512 + s * 128 + 2 * i;
  o[f] = packh2(p[0], p[1]);
}

// slots[l] is (65, 32, 256) u64. slot[0] prefilled with packed h0 (self-validating
// {pv, ~pv}); slots[1..64] zeroed ({0,0} fails hi==~lo -> "not ready").
__global__ __launch_bounds__(256) void slots_init(const float* __restrict__ h0,
                                                  unsigned long long* __restrict__ s0,
                                                  unsigned long long* __restrict__ s1) {
  const long N = 65L * 32 * 256;  // 532480 per layer
  for (long i = (long)blockIdx.x * 256 + threadIdx.x; i < 2 * N;
       i += (long)gridDim.x * 256) {
    int l = (int)(i / N);
    long r = i - (long)l * N;
    unsigned long long* dst = l ? s1 : s0;
    if (r < 32 * 256) {
      int b = (int)(r >> 8), p = (int)(r & 255);
      unsigned int pv = packh2(h0[l * 16384 + b * 512 + 2 * p],
                               h0[l * 16384 + b * 512 + 2 * p + 1]);
      dst[r] = (unsigned long long)pv | ((unsigned long long)(~pv) << 32);
    } else {
      dst[r] = 0ULL;
    }
  }
}

// enc (32,256,1024) f32 -> encT (32,1024,256) f16
__global__ void transpose_enc(const float* __restrict__ e, unsigned short* __restrict__ et) {
  __shared__ float t[32][33];
  int d0 = blockIdx.x * 32, s0 = blockIdx.y * 32, b = blockIdx.z;
  const float* eb = e + (long)b * 256 * 1024;
  for (int i = threadIdx.y; i < 32; i += 8)
    t[i][threadIdx.x] = eb[(long)(s0 + i) * 1024 + d0 + threadIdx.x];
  __syncthreads();
  unsigned short* eo = et + (long)b * 1024 * 256;
  for (int i = threadIdx.y; i < 32; i += 8)
    eo[(long)(d0 + i) * 256 + s0 + threadIdx.x] = f2h(t[threadIdx.x][i]);
}

// softmax over rows of 256 (scores f32 -> attn f16)
__global__ __launch_bounds__(256) void softmax_rows(const float* __restrict__ s,
                                                    unsigned short* __restrict__ a) {
  int row = blockIdx.x * 4 + (threadIdx.x >> 6);
  int lane = threadIdx.x & 63;
  const float* sr = s + (long)row * 256;
  float v[4], m = -1e30f;
#pragma unroll
  for (int i = 0; i < 4; i++) { v[i] = sr[lane + 64 * i]; m = fmaxf(m, v[i]); }
#pragma unroll
  for (int o = 32; o; o >>= 1) m = fmaxf(m, __shfl_xor(m, o));
  float sum = 0.f;
#pragma unroll
  for (int i = 0; i < 4; i++) { v[i] = __expf(v[i] - m); sum += v[i]; }
#pragma unroll
  for (int o = 32; o; o >>= 1) sum += __shfl_xor(sum, o);
  float inv = 1.f / sum;
#pragma unroll
  for (int i = 0; i < 4; i++) a[(long)row * 256 + lane + 64 * i] = f2h(v[i] * inv);
}

// ---------- MFMA GEMM: C(MxN) = A(MxK) * B(NxK)^T (+bias) (+relu) ----------
// MFAST: grid is (M-tiles, N-tiles) so concurrent blocks share B panels (L2/LLC reuse).
// LDS staging uses source-side XOR swizzle (c ^= ((r>>1)&3)<<3) + matching read-side
// XOR: spreads ds_read_b128 lanes across all 8 16B chunk positions (2-way = free).
template <int BM, int BN, int WM, int WN, bool OUT_F16, bool HAS_BIAS, bool RELU,
          bool MFAST = false>
__global__ __launch_bounds__(WM * WN * 64) void gemm_bt(
    const unsigned short* __restrict__ A, const unsigned short* __restrict__ B,
    void* __restrict__ Cv, const float* __restrict__ bias, int K, int lda, int ldb,
    int ldc, long sA, long sB, long sC) {
  constexpr int NT = WM * WN * 64;
  constexpr int IA = (BM * 32) / (NT * 8);
  constexpr int IB = (BN * 32) / (NT * 8);
  static_assert((BM * 32) % (NT * 8) == 0 && (BN * 32) % (NT * 8) == 0, "staging");
  __shared__ __align__(16) unsigned short As[BM * 32];
  __shared__ __align__(16) unsigned short Bs[BN * 32];
  const int tid = threadIdx.x;
  const int wave = tid >> 6, lane = tid & 63;
  const int wm = wave / WN, wn = wave % WN;
  const int lr = lane & 15, lq = lane >> 4;
  const long z = blockIdx.z;
  const int bxN = MFAST ? blockIdx.y : blockIdx.x;  // N-tile index
  const int byM = MFAST ? blockIdx.x : blockIdx.y;  // M-tile index
  const unsigned short* Ab = A + z * sA + (long)byM * BM * lda;
  const unsigned short* Bb = B + z * sB + (long)bxN * BN * ldb;

  f32x4 acc[4][4];
#pragma unroll
  for (int i = 0; i < 4; i++)
#pragma unroll
    for (int j = 0; j < 4; j++) acc[i][j] = (f32x4){0.f, 0.f, 0.f, 0.f};

  for (int k0 = 0; k0 < K; k0 += 32) {
#pragma unroll
    for (int i = 0; i < IA; i++) {
      int flat = (i * NT + tid) * 8;
      int r = flat >> 5, c = flat & 31;
      int cs = c ^ (((r >> 1) & 3) << 3);  // pre-swizzled source col
      stage16(Ab + (long)r * lda + k0 + cs, &As[(i * NT + wave * 64) * 8]);
    }
#pragma unroll
    for (int i = 0; i < IB; i++) {
      int flat = (i * NT + tid) * 8;
      int r = flat >> 5, c = flat & 31;
      int cs = c ^ (((r >> 1) & 3) << 3);
      stage16(Bb + (long)r * ldb + k0 + cs, &Bs[(i * NT + wave * 64) * 8]);
    }
    __syncthreads();
    half8 af[4], bf[4];
#pragma unroll
    for (int t = 0; t < 4; t++) {
      int ra = wm * 64 + t * 16 + lr;
      af[t] = *(const half8*)&As[ra * 32 + ((lq ^ ((ra >> 1) & 3)) << 3)];
    }
#pragma unroll
    for (int t = 0; t < 4; t++) {
      int rb = wn * 64 + t * 16 + lr;
      bf[t] = *(const half8*)&Bs[rb * 32 + ((lq ^ ((rb >> 1) & 3)) << 3)];
    }
#pragma unroll
    for (int ti = 0; ti < 4; ti++)
#pragma unroll
      for (int tj = 0; tj < 4; tj++)
        acc[ti][tj] = __builtin_amdgcn_mfma_f32_16x16x32_f16(af[ti], bf[tj],
                                                             acc[ti][tj], 0, 0, 0);
    __syncthreads();
  }

  const long crow0 = (long)byM * BM + wm * 64;
  const long ccol0 = (long)bxN * BN + wn * 64;
  float bv[4];
  if constexpr (HAS_BIAS) {
#pragma unroll
    for (int tj = 0; tj < 4; tj++) bv[tj] = bias[ccol0 + tj * 16 + lr];
  }
#pragma unroll
  for (int ti = 0; ti < 4; ti++)
#pragma unroll
    for (int tj = 0; tj < 4; tj++) {
      long col = ccol0 + tj * 16 + lr;
#pragma unroll
      for (int r = 0; r < 4; r++) {
        long row = crow0 + ti * 16 + lq * 4 + r;
        float v = acc[ti][tj][r];
        if constexpr (HAS_BIAS) v += bv[tj];
        if constexpr (RELU) v = fmaxf(v, 0.f);
        if constexpr (OUT_F16)
          ((unsigned short*)Cv)[z * sC + row * ldc + col] = f2h(v);
        else
          ((float*)Cv)[z * sC + row * ldc + col] = v;
      }
    }
}

// ---------- GRU scan v3: flagless self-validating slot exchange ----------
__global__ __launch_bounds__(256, 1) void gru_scan8(
    const float* __restrict__ gi,        // (2048, 1536) f32 (includes bih)
    const unsigned int* __restrict__ wp, // packed per pack_whh8
    const float* __restrict__ bhh,       // (1536,)
    const float* __restrict__ h0,        // (32, 512) f32 for this layer
    unsigned long long* __restrict__ slots,  // (65,32,256) u64, slot[0] prefilled
    unsigned short* __restrict__ out, int ldo) {
  const int b = blockIdx.x & 31;
  const int c = blockIdx.x >> 5;
  const int tid = threadIdx.x;
  const int ld = tid >> 2, s = tid & 3;
  const int dim = c * 64 + ld;
  __shared__ __align__(16) unsigned int hp[2][4 * 68];  // double-buffered h staging

  // load weights into registers (rows g*512+dim, K-slice s)
  unsigned int w0[64], w1[64], w2[64];
  {
    const uint4* p0 = (const uint4*)(wp + ((long)(0 * 512 + dim) * 4 + s) * 64);
    const uint4* p1 = (const uint4*)(wp + ((long)(512 + dim) * 4 + s) * 64);
    const uint4* p2 = (const uint4*)(wp + ((long)(1024 + dim) * 4 + s) * 64);
#pragma unroll
    for (int i = 0; i < 16; i++) {
      uint4 v = p0[i];
      w0[4 * i] = v.x; w0[4 * i + 1] = v.y; w0[4 * i + 2] = v.z; w0[4 * i + 3] = v.w;
    }
#pragma unroll
    for (int i = 0; i < 16; i++) {
      uint4 v = p1[i];
      w1[4 * i] = v.x; w1[4 * i + 1] = v.y; w1[4 * i + 2] = v.z; w1[4 * i + 3] = v.w;
    }
#pragma unroll
    for (int i = 0; i < 16; i++) {
      uint4 v = p2[i];
      w2[4 * i] = v.x; w2[4 * i + 1] = v.y; w2[4 * i + 2] = v.z; w2[4 * i + 3] = v.w;
    }
  }
  const bool lead = (s == 0);
  float hprev = 0.f, br = 0.f, bz = 0.f, bn = 0.f;
  if (lead) {
    hprev = h0[b * 512 + dim];
    br = bhh[dim]; bz = bhh[512 + dim]; bn = bhh[1024 + dim];
  }

  for (int t = 0; t < 64; t++) {
    const long row = (long)b * 64 + t;
    // gi loads: independent of h, issue before the poll so latency hides
    float gr = 0.f, gz = 0.f, gn = 0.f;
    if (lead) {
      gr = gi[row * 1536 + dim];
      gz = gi[row * 1536 + 512 + dim];
      gn = gi[row * 1536 + 1024 + dim];
    }
    // every thread polls exactly one self-validating u64 slot of h(t-1)
    {
      const unsigned long long* sp = slots + ((long)t * 32 + b) * 256 + tid;
      unsigned long long v =
          __hip_atomic_load(sp, __ATOMIC_RELAXED, __HIP_MEMORY_SCOPE_AGENT);
      unsigned int guard = 0;
      while ((unsigned int)(v >> 32) != ~(unsigned int)v) {
        __builtin_amdgcn_s_sleep(1);
        v = __hip_atomic_load(sp, __ATOMIC_RELAXED, __HIP_MEMORY_SCOPE_AGENT);
        if (++guard > (1u << 20)) break;  // safety valve, never expected
      }
      hp[t & 1][(tid >> 6) * 68 + (tid & 63)] = (unsigned int)v;
    }
    __syncthreads();
    // 3x128-MAC dot from register weights x LDS h-slice
    float ar = 0.f, az = 0.f, an = 0.f;
    const uint4* hv4 = (const uint4*)(hp[t & 1] + s * 68);
#pragma unroll
    for (int m = 0; m < 16; m++) {
      uint4 hv = hv4[m];
      ar = fdot2f(hv.x, w0[4 * m], ar);
      az = fdot2f(hv.x, w1[4 * m], az);
      an = fdot2f(hv.x, w2[4 * m], an);
      ar = fdot2f(hv.y, w0[4 * m + 1], ar);
      az = fdot2f(hv.y, w1[4 * m + 1], az);
      an = fdot2f(hv.y, w2[4 * m + 1], an);
      ar = fdot2f(hv.z, w0[4 * m + 2], ar);
      az = fdot2f(hv.z, w1[4 * m + 2], az);
      an = fdot2f(hv.z, w2[4 * m + 2], an);
      ar = fdot2f(hv.w, w0[4 * m + 3], ar);
      az = fdot2f(hv.w, w1[4 * m + 3], az);
      an = fdot2f(hv.w, w2[4 * m + 3], an);
    }
    ar += __shfl_xor(ar, 1); ar += __shfl_xor(ar, 2);
    az += __shfl_xor(az, 1); az += __shfl_xor(az, 2);
    an += __shfl_xor(an, 1); an += __shfl_xor(an, 2);
    float hn = 0.f;
    if (lead) {
      float r = fsigm(gr + br + ar);
      float zz = fsigm(gz + bz + az);
      float nn = ftanhf(gn + r * (an + bn));
      hn = (1.f - zz) * nn + zz * hprev;
      hprev = hn;
      out[row * ldo + dim] = f2h(hn);
    }
    // publish new h chunk: even-ld leaders pack pairs with their odd neighbor;
    // single atomic u64 store carries data + validity together.
    float ho = __shfl_xor(hn, 4);
    if (lead && ((ld & 1) == 0)) {
      unsigned int pv = packh2(hn, ho);
      unsigned long long pw =
          (unsigned long long)pv | ((unsigned long long)(~pv) << 32);
      __hip_atomic_store(slots + ((long)(t + 1) * 32 + b) * 256 + c * 32 + (ld >> 1),
                         pw, __ATOMIC_RELAXED, __HIP_MEMORY_SCOPE_AGENT);
    }
    // no trailing barrier: hp is double-buffered; the next iteration's single
    // barrier orders reads-at-t vs writes-at-t+2 (lgkmcnt(0) drains before barrier).
  }
}

// ---------- launch ----------
extern "C" void kernel_launch(void* const* d_in, const int* in_sizes, int n_in,
                              void* d_out, int out_size, void* d_ws, size_t ws_size,
                              hipStream_t stream) {
  const float* enc = (const float*)d_in[0];
  const float* ehid = (const float*)d_in[1];
  const int* words = (const int*)d_in[2];
  const float* embed = (const float*)d_in[3];
  const float* Wih0 = (const float*)d_in[4];
  const float* Whh0 = (const float*)d_in[5];
  const float* bih0 = (const float*)d_in[6];
  const float* bhh0 = (const float*)d_in[7];
  const float* Wih1 = (const float*)d_in[8];
  const float* Whh1 = (const float*)d_in[9];
  const float* bih1 = (const float*)d_in[10];
  const float* bhh1 = (const float*)d_in[11];
  const float* attW = (const float*)d_in[12];
  const float* attb = (const float*)d_in[13];
  const float* awW = (const float*)d_in[14];
  const float* awb = (const float*)d_in[15];
  const float* outW = (const float*)d_in[16];
  const float* outb = (const float*)d_in[17];
  float* out = (float*)d_out;

  char* ws = (char*)d_ws;
  size_t off = 0;
  auto alloc = [&](size_t bytes) {
    char* p = ws + off;
    off = (off + bytes + 255) & ~(size_t)255;
    return p;
  };
  unsigned short* xpad = (unsigned short*)alloc(2048ULL * 320 * 2);
  unsigned short* wih0p = (unsigned short*)alloc(1536ULL * 320 * 2);
  unsigned short* wih1b = (unsigned short*)alloc(1536ULL * 512 * 2);
  unsigned short* attwb = (unsigned short*)alloc(512ULL * 1024 * 2);
  unsigned short* awwb = (unsigned short*)alloc(1536ULL * 1536 * 2);
  unsigned short* outwb = (unsigned short*)alloc(32000ULL * 1536 * 2);
  unsigned short* encb = (unsigned short*)alloc(8192ULL * 1024 * 2);
  unsigned short* enct = (unsigned short*)alloc(32ULL * 1024 * 256 * 2);
  unsigned int* wp0 = (unsigned int*)alloc(393216ULL * 4);
  unsigned int* wp1 = (unsigned int*)alloc(393216ULL * 4);
  float* h0b = (float*)alloc(2ULL * 32 * 512 * 4);
  unsigned long long* slots0 = (unsigned long long*)alloc(65ULL * 32 * 256 * 8);
  unsigned long long* slots1 = (unsigned long long*)alloc(65ULL * 32 * 256 * 8);
  float* gi0 = (float*)alloc(2048ULL * 1536 * 4);
  float* gi1 = (float*)alloc(2048ULL * 1536 * 4);
  unsigned short* ys0 = (unsigned short*)alloc(2048ULL * 512 * 2);
  unsigned short* projb = (unsigned short*)alloc(8192ULL * 512 * 2);
  float* scores = (float*)alloc(2048ULL * 256 * 4);
  unsigned short* attnb = (unsigned short*)alloc(2048ULL * 256 * 2);
  unsigned short* catb = (unsigned short*)alloc(2048ULL * 1536 * 2);
  unsigned short* obuf = (unsigned short*)alloc(2048ULL * 1536 * 2);
  (void)ws_size; (void)in_sizes; (void)n_in; (void)out_size;

  // prep / converts
  cvt4<<<4096, 256, 0, stream>>>((const float4*)enc, (ushort4*)encb, 2097152);
  cvt4<<<1024, 256, 0, stream>>>((const float4*)attW, (ushort4*)attwb, 131072);
  cvt4<<<2048, 256, 0, stream>>>((const float4*)awW, (ushort4*)awwb, 589824);
  cvt4<<<4096, 256, 0, stream>>>((const float4*)outW, (ushort4*)outwb, 12288000);
  cvt4<<<768, 256, 0, stream>>>((const float4*)Wih1, (ushort4*)wih1b, 196608);
  cvt_pad_wih0<<<1920, 256, 0, stream>>>(Wih0, wih0p);
  transpose_enc<<<dim3(32, 8, 32), dim3(32, 8), 0, stream>>>(enc, enct);
  pack_whh8<<<1536, 256, 0, stream>>>(Whh0, wp0);
  pack_whh8<<<1536, 256, 0, stream>>>(Whh1, wp1);
  embed_relu<<<2560, 256, 0, stream>>>(words, embed, xpad);
  h0_sum<<<128, 256, 0, stream>>>(ehid, h0b);
  slots_init<<<4160, 256, 0, stream>>>(h0b, slots0, slots1);

  // gi0 = x @ Wih0^T + bih0   (M=2048,K=320,N=1536) fp32
  gemm_bt<128, 128, 2, 2, false, true, false><<<dim3(12, 16, 1), 256, 0, stream>>>(
      xpad, wih0p, gi0, bih0, 320, 320, 320, 1536, 0, 0, 0);
  // GRU layer 0 -> ys0 f16
  gru_scan8<<<256, 256, 0, stream>>>(gi0, wp0, bhh0, h0b, slots0, ys0, 512);
  // gi1 = ys0 @ Wih1^T + bih1
  gemm_bt<128, 128, 2, 2, false, true, false><<<dim3(12, 16, 1), 256, 0, stream>>>(
      ys0, wih1b, gi1, bih1, 512, 512, 512, 1536, 0, 0, 0);
  // GRU layer 1 -> cat[:, 0:512] f16
  gru_scan8<<<256, 256, 0, stream>>>(gi1, wp1, bhh1, h0b + 16384, slots1,
                                     catb, 1536);
  // proj = enc @ attn_W^T + attn_b  (M=8192,K=1024,N=512) f16
  gemm_bt<128, 128, 2, 2, true, true, false><<<dim3(4, 64, 1), 256, 0, stream>>>(
      encb, attwb, projb, attb, 1024, 1024, 1024, 512, 0, 0, 0);
  // scores[b] = h[b] @ proj[b]^T  (batched M=64,N=256,K=512) fp32
  gemm_bt<64, 128, 1, 2, false, false, false><<<dim3(2, 1, 32), 128, 0, stream>>>(
      catb, projb, scores, nullptr, 512, 1536, 512, 256,
      64L * 1536, 256L * 512, 64L * 256);
  softmax_rows<<<512, 256, 0, stream>>>(scores, attnb);
  // ctx[b] = attn[b] @ encT[b]^T  (batched M=64,N=1024,K=256) -> cat[:, 512:]
  gemm_bt<64, 128, 1, 2, true, false, false><<<dim3(8, 1, 32), 128, 0, stream>>>(
      attnb, enct, catb + 512, nullptr, 256, 256, 256, 1536,
      64L * 256, 1024L * 256, 64L * 1536);
  // o = relu(cat @ aw_W^T + aw_b)  (M=2048,K=1536,N=1536) f16
  gemm_bt<128, 128, 2, 2, true, true, true><<<dim3(12, 16, 1), 256, 0, stream>>>(
      catb, awwb, obuf, awb, 1536, 1536, 1536, 1536, 0, 0, 0);
  // logits = o @ out_W^T + out_b  (M=2048,K=1536,N=32000) fp32 -> d_out
  // MFAST: M-tiles fast so concurrent blocks share B panels -> B fetched ~once.
  gemm_bt<128, 128, 2, 2, false, true, false, true><<<dim3(16, 250, 1), 256, 0, stream>>>(
      obuf, outwb, out, outb, 1536, 1536, 1536, 32000, 0, 0, 0);
}

// Round 5
// 1094.126 us; speedup vs baseline: 5.0314x; 1.0193x over previous
//
#include <hip/hip_runtime.h>

// ---------- types & helpers ----------
typedef _Float16 half8 __attribute__((ext_vector_type(8)));
typedef float f32x4 __attribute__((ext_vector_type(4)));
typedef _Float16 half2_t __attribute__((ext_vector_type(2)));
typedef const void __attribute__((address_space(1)))* gas_cptr;
typedef void __attribute__((address_space(3)))* las_ptr;

__device__ __forceinline__ unsigned short f2h(float f) {
  return __builtin_bit_cast(unsigned short, (_Float16)f);
}
__device__ __forceinline__ unsigned int packh2(float a, float b) {
  unsigned short lo = __builtin_bit_cast(unsigned short, (_Float16)a);
  unsigned short hi = __builtin_bit_cast(unsigned short, (_Float16)b);
  return (unsigned int)lo | ((unsigned int)hi << 16);
}
__device__ __forceinline__ float fdot2f(unsigned int a, unsigned int b, float c) {
#if __has_builtin(__builtin_amdgcn_fdot2)
  return __builtin_amdgcn_fdot2(__builtin_bit_cast(half2_t, a),
                                __builtin_bit_cast(half2_t, b), c, false);
#else
  half2_t ha = __builtin_bit_cast(half2_t, a), hb = __builtin_bit_cast(half2_t, b);
  return c + (float)ha[0] * (float)hb[0] + (float)ha[1] * (float)hb[1];
#endif
}
__device__ __forceinline__ float fsigm(float x) {
  x = fminf(15.f, fmaxf(-15.f, x));
  return 1.f / (1.f + __expf(-x));
}
__device__ __forceinline__ float ftanhf(float x) {
  x = fminf(15.f, fmaxf(-15.f, x));
  float e = __expf(-2.f * x);
  return (1.f - e) / (1.f + e);
}
__device__ __forceinline__ void stage16(const void* g, void* l) {
  __builtin_amdgcn_global_load_lds((gas_cptr)g, (las_ptr)l, 16, 0, 0);
}

// ---------- small prep kernels ----------
__global__ __launch_bounds__(256) void cvt4(const float4* __restrict__ in,
                                            ushort4* __restrict__ out, int n4) {
  for (int i = blockIdx.x * 256 + threadIdx.x; i < n4; i += gridDim.x * 256) {
    float4 v = in[i];
    ushort4 r;
    r.x = f2h(v.x); r.y = f2h(v.y); r.z = f2h(v.z); r.w = f2h(v.w);
    out[i] = r;
  }
}

// Wih0 (1536 x 300) -> f16 zero-padded to (1536 x 320)
__global__ __launch_bounds__(256) void cvt_pad_wih0(const float* __restrict__ W,
                                                    unsigned short* __restrict__ o) {
  int idx = blockIdx.x * 256 + threadIdx.x;  // < 1536*320
  if (idx >= 1536 * 320) return;
  int r = idx / 320, c = idx - r * 320;
  float v = (c < 300) ? W[(long)r * 300 + c] : 0.f;
  o[idx] = f2h(v);
}

// x = relu(embed[words[:, :-1]]) -> f16, padded E 300->320
__global__ __launch_bounds__(256) void embed_relu(const int* __restrict__ words,
                                                  const float* __restrict__ emb,
                                                  unsigned short* __restrict__ x) {
  int idx = blockIdx.x * 256 + threadIdx.x;  // < 2048*320
  if (idx >= 2048 * 320) return;
  int row = idx / 320, e = idx - row * 320;
  int b = row >> 6, t = row & 63;
  int w = words[b * 65 + t];
  float v = 0.f;
  if (e < 300) v = fmaxf(emb[(long)w * 300 + e], 0.f);
  x[idx] = f2h(v);
}

// h0[l] = encoder_hidden[l] + encoder_hidden[2+l]  (layout (2L,B,H)=(4,32,512))
__global__ __launch_bounds__(256) void h0_sum(const float* __restrict__ hid,
                                              float* __restrict__ h0) {
  int idx = blockIdx.x * 256 + threadIdx.x;  // < 32768
  if (idx >= 2 * 32 * 512) return;
  int l = idx >> 14, rem = idx & 16383;
  h0[idx] = hid[l * 16384 + rem] + hid[(2 + l) * 16384 + rem];
}

// Whh (1536x512 f32) -> per-thread-sliced f16 pairs:
// o[((row)*4 + s)*64 + i] = pack(W[row][s*128+2i], W[row][s*128+2i+1]), row=g*512+dim
__global__ __launch_bounds__(256) void pack_whh8(const float* __restrict__ W,
                                                 unsigned int* __restrict__ o) {
  int f = blockIdx.x * 256 + threadIdx.x;  // < 1536*256 = 393216
  if (f >= 393216) return;
  int i = f & 63;
  int s = (f >> 6) & 3;
  int row = f >> 8;  // 0..1535
  const float* p = W + (long)row * 512 + s * 128 + 2 * i;
  o[f] = packh2(p[0], p[1]);
}

// slots[l] is (65, 32, 256) u64. slot[0] prefilled with packed h0 (self-validating
// {pv, ~pv}); slots[1..64] zeroed ({0,0} fails hi==~lo -> "not ready").
__global__ __launch_bounds__(256) void slots_init(const float* __restrict__ h0,
                                                  unsigned long long* __restrict__ s0,
                                                  unsigned long long* __restrict__ s1) {
  const long N = 65L * 32 * 256;  // 532480 per layer
  for (long i = (long)blockIdx.x * 256 + threadIdx.x; i < 2 * N;
       i += (long)gridDim.x * 256) {
    int l = (int)(i / N);
    long r = i - (long)l * N;
    unsigned long long* dst = l ? s1 : s0;
    if (r < 32 * 256) {
      int b = (int)(r >> 8), p = (int)(r & 255);
      unsigned int pv = packh2(h0[l * 16384 + b * 512 + 2 * p],
                               h0[l * 16384 + b * 512 + 2 * p + 1]);
      dst[r] = (unsigned long long)pv | ((unsigned long long)(~pv) << 32);
    } else {
      dst[r] = 0ULL;
    }
  }
}

// enc (32,256,1024) f32 -> encT (32,1024,256) f16
__global__ void transpose_enc(const float* __restrict__ e, unsigned short* __restrict__ et) {
  __shared__ float t[32][33];
  int d0 = blockIdx.x * 32, s0 = blockIdx.y * 32, b = blockIdx.z;
  const float* eb = e + (long)b * 256 * 1024;
  for (int i = threadIdx.y; i < 32; i += 8)
    t[i][threadIdx.x] = eb[(long)(s0 + i) * 1024 + d0 + threadIdx.x];
  __syncthreads();
  unsigned short* eo = et + (long)b * 1024 * 256;
  for (int i = threadIdx.y; i < 32; i += 8)
    eo[(long)(d0 + i) * 256 + s0 + threadIdx.x] = f2h(t[threadIdx.x][i]);
}

// softmax over rows of 256 (scores f32 -> attn f16)
__global__ __launch_bounds__(256) void softmax_rows(const float* __restrict__ s,
                                                    unsigned short* __restrict__ a) {
  int row = blockIdx.x * 4 + (threadIdx.x >> 6);
  int lane = threadIdx.x & 63;
  const float* sr = s + (long)row * 256;
  float v[4], m = -1e30f;
#pragma unroll
  for (int i = 0; i < 4; i++) { v[i] = sr[lane + 64 * i]; m = fmaxf(m, v[i]); }
#pragma unroll
  for (int o = 32; o; o >>= 1) m = fmaxf(m, __shfl_xor(m, o));
  float sum = 0.f;
#pragma unroll
  for (int i = 0; i < 4; i++) { v[i] = __expf(v[i] - m); sum += v[i]; }
#pragma unroll
  for (int o = 32; o; o >>= 1) sum += __shfl_xor(sum, o);
  float inv = 1.f / sum;
#pragma unroll
  for (int i = 0; i < 4; i++) a[(long)row * 256 + lane + 64 * i] = f2h(v[i] * inv);
}

// ---------- MFMA GEMM: C(MxN) = A(MxK) * B(NxK)^T (+bias) (+relu) ----------
// 2-phase double-buffered (T3 minimum recipe): stage tile t+1 into buf^1 BEFORE
// computing tile t from buf, one vmcnt-drain+barrier per tile (inside
// __syncthreads). Staging latency (LLC ~600-900cy) overlaps current-tile compute.
// MFAST: grid is (M-tiles, N-tiles) so concurrent blocks share B panels.
// LDS staging uses source-side XOR swizzle + matching read-side XOR (0 conflicts).
template <int BM, int BN, int WM, int WN, bool OUT_F16, bool HAS_BIAS, bool RELU,
          bool MFAST = false>
__global__ __launch_bounds__(WM * WN * 64) void gemm_bt(
    const unsigned short* __restrict__ A, const unsigned short* __restrict__ B,
    void* __restrict__ Cv, const float* __restrict__ bias, int K, int lda, int ldb,
    int ldc, long sA, long sB, long sC) {
  constexpr int NT = WM * WN * 64;
  constexpr int IA = (BM * 32) / (NT * 8);
  constexpr int IB = (BN * 32) / (NT * 8);
  static_assert((BM * 32) % (NT * 8) == 0 && (BN * 32) % (NT * 8) == 0, "staging");
  __shared__ __align__(16) unsigned short As[2][BM * 32];
  __shared__ __align__(16) unsigned short Bs[2][BN * 32];
  const int tid = threadIdx.x;
  const int wave = tid >> 6, lane = tid & 63;
  const int wm = wave / WN, wn = wave % WN;
  const int lr = lane & 15, lq = lane >> 4;
  const long z = blockIdx.z;
  const int bxN = MFAST ? blockIdx.y : blockIdx.x;  // N-tile index
  const int byM = MFAST ? blockIdx.x : blockIdx.y;  // M-tile index
  const unsigned short* Ab = A + z * sA + (long)byM * BM * lda;
  const unsigned short* Bb = B + z * sB + (long)bxN * BN * ldb;

  auto stage_tile = [&](int k0, int buf) {
#pragma unroll
    for (int i = 0; i < IA; i++) {
      int flat = (i * NT + tid) * 8;
      int r = flat >> 5, c = flat & 31;
      int cs = c ^ (((r >> 1) & 3) << 3);  // pre-swizzled source col
      stage16(Ab + (long)r * lda + k0 + cs, &As[buf][(i * NT + wave * 64) * 8]);
    }
#pragma unroll
    for (int i = 0; i < IB; i++) {
      int flat = (i * NT + tid) * 8;
      int r = flat >> 5, c = flat & 31;
      int cs = c ^ (((r >> 1) & 3) << 3);
      stage16(Bb + (long)r * ldb + k0 + cs, &Bs[buf][(i * NT + wave * 64) * 8]);
    }
  };

  f32x4 acc[4][4];
#pragma unroll
  for (int i = 0; i < 4; i++)
#pragma unroll
    for (int j = 0; j < 4; j++) acc[i][j] = (f32x4){0.f, 0.f, 0.f, 0.f};

  stage_tile(0, 0);
  __syncthreads();  // drains vmcnt(0): buf0 ready
  int cur = 0;
  for (int k0 = 0; k0 < K; k0 += 32) {
    if (k0 + 32 < K) stage_tile(k0 + 32, cur ^ 1);  // prefetch next tile
    half8 af[4], bf[4];
#pragma unroll
    for (int t = 0; t < 4; t++) {
      int ra = wm * 64 + t * 16 + lr;
      af[t] = *(const half8*)&As[cur][ra * 32 + ((lq ^ ((ra >> 1) & 3)) << 3)];
    }
#pragma unroll
    for (int t = 0; t < 4; t++) {
      int rb = wn * 64 + t * 16 + lr;
      bf[t] = *(const half8*)&Bs[cur][rb * 32 + ((lq ^ ((rb >> 1) & 3)) << 3)];
    }
#pragma unroll
    for (int ti = 0; ti < 4; ti++)
#pragma unroll
      for (int tj = 0; tj < 4; tj++)
        acc[ti][tj] = __builtin_amdgcn_mfma_f32_16x16x32_f16(af[ti], bf[tj],
                                                             acc[ti][tj], 0, 0, 0);
    __syncthreads();  // one drain+barrier per K-tile: next buf staged, cur reads done
    cur ^= 1;
  }

  const long crow0 = (long)byM * BM + wm * 64;
  const long ccol0 = (long)bxN * BN + wn * 64;
  float bv[4];
  if constexpr (HAS_BIAS) {
#pragma unroll
    for (int tj = 0; tj < 4; tj++) bv[tj] = bias[ccol0 + tj * 16 + lr];
  }
#pragma unroll
  for (int ti = 0; ti < 4; ti++)
#pragma unroll
    for (int tj = 0; tj < 4; tj++) {
      long col = ccol0 + tj * 16 + lr;
#pragma unroll
      for (int r = 0; r < 4; r++) {
        long row = crow0 + ti * 16 + lq * 4 + r;
        float v = acc[ti][tj][r];
        if constexpr (HAS_BIAS) v += bv[tj];
        if constexpr (RELU) v = fmaxf(v, 0.f);
        if constexpr (OUT_F16)
          ((unsigned short*)Cv)[z * sC + row * ldc + col] = f2h(v);
        else
          ((float*)Cv)[z * sC + row * ldc + col] = v;
      }
    }
}

// ---------- GRU scan v3: flagless self-validating slot exchange ----------
__global__ __launch_bounds__(256, 1) void gru_scan8(
    const float* __restrict__ gi,        // (2048, 1536) f32 (includes bih)
    const unsigned int* __restrict__ wp, // packed per pack_whh8
    const float* __restrict__ bhh,       // (1536,)
    const float* __restrict__ h0,        // (32, 512) f32 for this layer
    unsigned long long* __restrict__ slots,  // (65,32,256) u64, slot[0] prefilled
    unsigned short* __restrict__ out, int ldo) {
  const int b = blockIdx.x & 31;
  const int c = blockIdx.x >> 5;
  const int tid = threadIdx.x;
  const int ld = tid >> 2, s = tid & 3;
  const int dim = c * 64 + ld;
  __shared__ __align__(16) unsigned int hp[2][4 * 68];  // double-buffered h staging

  // load weights into registers (rows g*512+dim, K-slice s)
  unsigned int w0[64], w1[64], w2[64];
  {
    const uint4* p0 = (const uint4*)(wp + ((long)(0 * 512 + dim) * 4 + s) * 64);
    const uint4* p1 = (const uint4*)(wp + ((long)(512 + dim) * 4 + s) * 64);
    const uint4* p2 = (const uint4*)(wp + ((long)(1024 + dim) * 4 + s) * 64);
#pragma unroll
    for (int i = 0; i < 16; i++) {
      uint4 v = p0[i];
      w0[4 * i] = v.x; w0[4 * i + 1] = v.y; w0[4 * i + 2] = v.z; w0[4 * i + 3] = v.w;
    }
#pragma unroll
    for (int i = 0; i < 16; i++) {
      uint4 v = p1[i];
      w1[4 * i] = v.x; w1[4 * i + 1] = v.y; w1[4 * i + 2] = v.z; w1[4 * i + 3] = v.w;
    }
#pragma unroll
    for (int i = 0; i < 16; i++) {
      uint4 v = p2[i];
      w2[4 * i] = v.x; w2[4 * i + 1] = v.y; w2[4 * i + 2] = v.z; w2[4 * i + 3] = v.w;
    }
  }
  const bool lead = (s == 0);
  float hprev = 0.f, br = 0.f, bz = 0.f, bn = 0.f;
  if (lead) {
    hprev = h0[b * 512 + dim];
    br = bhh[dim]; bz = bhh[512 + dim]; bn = bhh[1024 + dim];
  }

  for (int t = 0; t < 64; t++) {
    const long row = (long)b * 64 + t;
    // gi loads: independent of h, issue before the poll so latency hides
    float gr = 0.f, gz = 0.f, gn = 0.f;
    if (lead) {
      gr = gi[row * 1536 + dim];
      gz = gi[row * 1536 + 512 + dim];
      gn = gi[row * 1536 + 1024 + dim];
    }
    // every thread polls exactly one self-validating u64 slot of h(t-1)
    {
      const unsigned long long* sp = slots + ((long)t * 32 + b) * 256 + tid;
      unsigned long long v =
          __hip_atomic_load(sp, __ATOMIC_RELAXED, __HIP_MEMORY_SCOPE_AGENT);
      unsigned int guard = 0;
      while ((unsigned int)(v >> 32) != ~(unsigned int)v) {
        __builtin_amdgcn_s_sleep(1);
        v = __hip_atomic_load(sp, __ATOMIC_RELAXED, __HIP_MEMORY_SCOPE_AGENT);
        if (++guard > (1u << 20)) break;  // safety valve, never expected
      }
      hp[t & 1][(tid >> 6) * 68 + (tid & 63)] = (unsigned int)v;
    }
    __syncthreads();
    // 3x128-MAC dot from register weights x LDS h-slice
    float ar = 0.f, az = 0.f, an = 0.f;
    const uint4* hv4 = (const uint4*)(hp[t & 1] + s * 68);
#pragma unroll
    for (int m = 0; m < 16; m++) {
      uint4 hv = hv4[m];
      ar = fdot2f(hv.x, w0[4 * m], ar);
      az = fdot2f(hv.x, w1[4 * m], az);
      an = fdot2f(hv.x, w2[4 * m], an);
      ar = fdot2f(hv.y, w0[4 * m + 1], ar);
      az = fdot2f(hv.y, w1[4 * m + 1], az);
      an = fdot2f(hv.y, w2[4 * m + 1], an);
      ar = fdot2f(hv.z, w0[4 * m + 2], ar);
      az = fdot2f(hv.z, w1[4 * m + 2], az);
      an = fdot2f(hv.z, w2[4 * m + 2], an);
      ar = fdot2f(hv.w, w0[4 * m + 3], ar);
      az = fdot2f(hv.w, w1[4 * m + 3], az);
      an = fdot2f(hv.w, w2[4 * m + 3], an);
    }
    ar += __shfl_xor(ar, 1); ar += __shfl_xor(ar, 2);
    az += __shfl_xor(az, 1); az += __shfl_xor(az, 2);
    an += __shfl_xor(an, 1); an += __shfl_xor(an, 2);
    float hn = 0.f;
    if (lead) {
      float r = fsigm(gr + br + ar);
      float zz = fsigm(gz + bz + az);
      float nn = ftanhf(gn + r * (an + bn));
      hn = (1.f - zz) * nn + zz * hprev;
      hprev = hn;
      out[row * ldo + dim] = f2h(hn);
    }
    // publish new h chunk: even-ld leaders pack pairs with their odd neighbor;
    // single atomic u64 store carries data + validity together.
    float ho = __shfl_xor(hn, 4);
    if (lead && ((ld & 1) == 0)) {
      unsigned int pv = packh2(hn, ho);
      unsigned long long pw =
          (unsigned long long)pv | ((unsigned long long)(~pv) << 32);
      __hip_atomic_store(slots + ((long)(t + 1) * 32 + b) * 256 + c * 32 + (ld >> 1),
                         pw, __ATOMIC_RELAXED, __HIP_MEMORY_SCOPE_AGENT);
    }
    // no trailing barrier: hp is double-buffered; the next iteration's single
    // barrier orders reads-at-t vs writes-at-t+2 (lgkmcnt(0) drains before barrier).
  }
}

// ---------- launch ----------
extern "C" void kernel_launch(void* const* d_in, const int* in_sizes, int n_in,
                              void* d_out, int out_size, void* d_ws, size_t ws_size,
                              hipStream_t stream) {
  const float* enc = (const float*)d_in[0];
  const float* ehid = (const float*)d_in[1];
  const int* words = (const int*)d_in[2];
  const float* embed = (const float*)d_in[3];
  const float* Wih0 = (const float*)d_in[4];
  const float* Whh0 = (const float*)d_in[5];
  const float* bih0 = (const float*)d_in[6];
  const float* bhh0 = (const float*)d_in[7];
  const float* Wih1 = (const float*)d_in[8];
  const float* Whh1 = (const float*)d_in[9];
  const float* bih1 = (const float*)d_in[10];
  const float* bhh1 = (const float*)d_in[11];
  const float* attW = (const float*)d_in[12];
  const float* attb = (const float*)d_in[13];
  const float* awW = (const float*)d_in[14];
  const float* awb = (const float*)d_in[15];
  const float* outW = (const float*)d_in[16];
  const float* outb = (const float*)d_in[17];
  float* out = (float*)d_out;

  char* ws = (char*)d_ws;
  size_t off = 0;
  auto alloc = [&](size_t bytes) {
    char* p = ws + off;
    off = (off + bytes + 255) & ~(size_t)255;
    return p;
  };
  unsigned short* xpad = (unsigned short*)alloc(2048ULL * 320 * 2);
  unsigned short* wih0p = (unsigned short*)alloc(1536ULL * 320 * 2);
  unsigned short* wih1b = (unsigned short*)alloc(1536ULL * 512 * 2);
  unsigned short* attwb = (unsigned short*)alloc(512ULL * 1024 * 2);
  unsigned short* awwb = (unsigned short*)alloc(1536ULL * 1536 * 2);
  unsigned short* outwb = (unsigned short*)alloc(32000ULL * 1536 * 2);
  unsigned short* encb = (unsigned short*)alloc(8192ULL * 1024 * 2);
  unsigned short* enct = (unsigned short*)alloc(32ULL * 1024 * 256 * 2);
  unsigned int* wp0 = (unsigned int*)alloc(393216ULL * 4);
  unsigned int* wp1 = (unsigned int*)alloc(393216ULL * 4);
  float* h0b = (float*)alloc(2ULL * 32 * 512 * 4);
  unsigned long long* slots0 = (unsigned long long*)alloc(65ULL * 32 * 256 * 8);
  unsigned long long* slots1 = (unsigned long long*)alloc(65ULL * 32 * 256 * 8);
  float* gi0 = (float*)alloc(2048ULL * 1536 * 4);
  float* gi1 = (float*)alloc(2048ULL * 1536 * 4);
  unsigned short* ys0 = (unsigned short*)alloc(2048ULL * 512 * 2);
  unsigned short* projb = (unsigned short*)alloc(8192ULL * 512 * 2);
  float* scores = (float*)alloc(2048ULL * 256 * 4);
  unsigned short* attnb = (unsigned short*)alloc(2048ULL * 256 * 2);
  unsigned short* catb = (unsigned short*)alloc(2048ULL * 1536 * 2);
  unsigned short* obuf = (unsigned short*)alloc(2048ULL * 1536 * 2);
  (void)ws_size; (void)in_sizes; (void)n_in; (void)out_size;

  // prep / converts
  cvt4<<<4096, 256, 0, stream>>>((const float4*)enc, (ushort4*)encb, 2097152);
  cvt4<<<1024, 256, 0, stream>>>((const float4*)attW, (ushort4*)attwb, 131072);
  cvt4<<<2048, 256, 0, stream>>>((const float4*)awW, (ushort4*)awwb, 589824);
  cvt4<<<4096, 256, 0, stream>>>((const float4*)outW, (ushort4*)outwb, 12288000);
  cvt4<<<768, 256, 0, stream>>>((const float4*)Wih1, (ushort4*)wih1b, 196608);
  cvt_pad_wih0<<<1920, 256, 0, stream>>>(Wih0, wih0p);
  transpose_enc<<<dim3(32, 8, 32), dim3(32, 8), 0, stream>>>(enc, enct);
  pack_whh8<<<1536, 256, 0, stream>>>(Whh0, wp0);
  pack_whh8<<<1536, 256, 0, stream>>>(Whh1, wp1);
  embed_relu<<<2560, 256, 0, stream>>>(words, embed, xpad);
  h0_sum<<<128, 256, 0, stream>>>(ehid, h0b);
  slots_init<<<4160, 256, 0, stream>>>(h0b, slots0, slots1);

  // gi0 = x @ Wih0^T + bih0   (M=2048,K=320,N=1536) fp32
  gemm_bt<128, 128, 2, 2, false, true, false><<<dim3(12, 16, 1), 256, 0, stream>>>(
      xpad, wih0p, gi0, bih0, 320, 320, 320, 1536, 0, 0, 0);
  // GRU layer 0 -> ys0 f16
  gru_scan8<<<256, 256, 0, stream>>>(gi0, wp0, bhh0, h0b, slots0, ys0, 512);
  // gi1 = ys0 @ Wih1^T + bih1
  gemm_bt<128, 128, 2, 2, false, true, false><<<dim3(12, 16, 1), 256, 0, stream>>>(
      ys0, wih1b, gi1, bih1, 512, 512, 512, 1536, 0, 0, 0);
  // GRU layer 1 -> cat[:, 0:512] f16
  gru_scan8<<<256, 256, 0, stream>>>(gi1, wp1, bhh1, h0b + 16384, slots1,
                                     catb, 1536);
  // proj = enc @ attn_W^T + attn_b  (M=8192,K=1024,N=512) f16
  gemm_bt<128, 128, 2, 2, true, true, false><<<dim3(4, 64, 1), 256, 0, stream>>>(
      encb, attwb, projb, attb, 1024, 1024, 1024, 512, 0, 0, 0);
  // scores[b] = h[b] @ proj[b]^T  (batched M=64,N=256,K=512) fp32
  gemm_bt<64, 128, 1, 2, false, false, false><<<dim3(2, 1, 32), 128, 0, stream>>>(
      catb, projb, scores, nullptr, 512, 1536, 512, 256,
      64L * 1536, 256L * 512, 64L * 256);
  softmax_rows<<<512, 256, 0, stream>>>(scores, attnb);
  // ctx[b] = attn[b] @ encT[b]^T  (batched M=64,N=1024,K=256) -> cat[:, 512:]
  gemm_bt<64, 128, 1, 2, true, false, false><<<dim3(8, 1, 32), 128, 0, stream>>>(
      attnb, enct, catb + 512, nullptr, 256, 256, 256, 1536,
      64L * 256, 1024L * 256, 64L * 1536);
  // o = relu(cat @ aw_W^T + aw_b)  (M=2048,K=1536,N=1536) f16
  gemm_bt<128, 128, 2, 2, true, true, true><<<dim3(12, 16, 1), 256, 0, stream>>>(
      catb, awwb, obuf, awb, 1536, 1536, 1536, 1536, 0, 0, 0);
  // logits = o @ out_W^T + out_b  (M=2048,K=1536,N=32000) fp32 -> d_out
  // MFAST: M-tiles fast so concurrent blocks share B panels -> B fetched ~once.
  gemm_bt<128, 128, 2, 2, false, true, false, true><<<dim3(16, 250, 1), 256, 0, stream>>>(
      obuf, outwb, out, outb, 1536, 1536, 1536, 32000, 0, 0, 0);
}